// Round 8
// baseline (1766.005 us; speedup 1.0000x reference)
//
#include <hip/hip_runtime.h>
#include <hip/hip_bf16.h>

typedef __hip_bfloat16 bf16;
typedef __attribute__((ext_vector_type(8))) short bf16x8;   // 8 bf16 = 4 VGPR
typedef __attribute__((ext_vector_type(4))) float f32x4;    // MFMA accumulator

__device__ __forceinline__ float b2f(bf16 v) { return __bfloat162float(v); }
__device__ __forceinline__ bf16 f2b(float v) { return __float2bfloat16(v); }
__device__ __forceinline__ unsigned short f2bb(float v) {   // RNE f32->bf16 bits
    unsigned int u = __float_as_uint(v);
    u += 0x7fffu + ((u >> 16) & 1u);
    return (unsigned short)(u >> 16);
}
// bf16x8 element k (compile-time k) -> f32 via bit shift
__device__ __forceinline__ float b2fx(bf16x8 v, int k) {
    return __uint_as_float(((unsigned int)(unsigned short)v[k]) << 16);
}

__device__ __forceinline__ f32x4 mfma16(bf16x8 a, bf16x8 b, f32x4 c) {
    return __builtin_amdgcn_mfma_f32_16x16x32_bf16(a, b, c, 0, 0, 0);
}

// Gather a B-fragment: rows k0..k0+7 of column col from row-major W[64][64] f32.
__device__ __forceinline__ bf16x8 load_bfrag(const float* __restrict__ W, int k0, int col) {
    bf16x8 f;
#pragma unroll
    for (int j = 0; j < 8; ++j)
        f[j] = (short)f2bb(W[(size_t)(k0 + j) * 64 + col]);
    return f;
}

// Swizzled byte offsets (G4: XOR row-bits into the 16B-slot index).
__device__ __forceinline__ int swzA(int row, int b) {   // [64][128 bf16] tile, 256B rows
    return row * 256 + (b ^ ((row & 7) << 4));
}
__device__ __forceinline__ int swzH(int row, int b) {   // [64][64 bf16] tile, 128B rows
    return row * 128 + (b ^ ((row & 7) << 4));
}

// ======================= CSR build =======================
__global__ void count_int_kernel(const int* __restrict__ dst, int* __restrict__ deg, int ne) {
    int e = blockIdx.x * 256 + threadIdx.x;
    if (e < ne) atomicAdd(&deg[dst[e]], 1);
}

// block-local exclusive scan over 1024 elems (256 thr x 4); writes block totals
__global__ void scan1_kernel(const int* __restrict__ deg, int* __restrict__ excl,
                             int* __restrict__ partial, int n) {
    __shared__ int sT[256];
    int tid = threadIdx.x;
    int base = blockIdx.x * 1024 + tid * 4;
    int v0 = (base + 0 < n) ? deg[base + 0] : 0;
    int v1 = (base + 1 < n) ? deg[base + 1] : 0;
    int v2 = (base + 2 < n) ? deg[base + 2] : 0;
    int v3 = (base + 3 < n) ? deg[base + 3] : 0;
    int t = v0 + v1 + v2 + v3;
    sT[tid] = t;
    __syncthreads();
    for (int off = 1; off < 256; off <<= 1) {   // Hillis-Steele inclusive
        int x = (tid >= off) ? sT[tid - off] : 0;
        __syncthreads();
        sT[tid] += x;
        __syncthreads();
    }
    int et = sT[tid] - t;
    if (tid == 255) partial[blockIdx.x] = sT[255];
    if (base + 0 < n) excl[base + 0] = et;
    if (base + 1 < n) excl[base + 1] = et + v0;
    if (base + 2 < n) excl[base + 2] = et + v0 + v1;
    if (base + 3 < n) excl[base + 3] = et + v0 + v1 + v2;
}

// single-block exclusive scan of the partials (np <= a few thousand)
__global__ void scan2_kernel(int* __restrict__ partial, int np) {
    __shared__ int sT[256];
    __shared__ int carry;
    int tid = threadIdx.x;
    if (tid == 0) carry = 0;
    __syncthreads();
    for (int c = 0; c < np; c += 256) {
        int i = c + tid;
        int v = (i < np) ? partial[i] : 0;
        sT[tid] = v;
        __syncthreads();
        for (int off = 1; off < 256; off <<= 1) {
            int x = (tid >= off) ? sT[tid - off] : 0;
            __syncthreads();
            sT[tid] += x;
            __syncthreads();
        }
        int incl = sT[tid];
        int total = sT[255];
        if (i < np) partial[i] = carry + incl - v;
        __syncthreads();
        if (tid == 0) carry += total;
        __syncthreads();
    }
}

// rowptr[i] = cursor[i] = excl[i] + partial[i>>10]  (cursor may alias excl)
__global__ void scan3_kernel(const int* __restrict__ excl, const int* __restrict__ partial,
                             int* __restrict__ rowptr, int* __restrict__ cursor, int n) {
    int i = blockIdx.x * 256 + threadIdx.x;
    if (i < n) {
        int v = excl[i] + partial[i >> 10];
        rowptr[i] = v;
        cursor[i] = v;
    }
}

__global__ void scatter_kernel(const int* __restrict__ src, const int* __restrict__ dst,
                               int* __restrict__ cursor, int* __restrict__ col, int ne) {
    int e = blockIdx.x * 256 + threadIdx.x;
    if (e < ne) {
        int p = atomicAdd(&cursor[dst[e]], 1);
        col[p] = src[e];
    }
}

// 8-accumulator macro for the in-register gather (named scalars, no arrays)
#define GM_ACC(x, w) \
    a0 += (w) * b2fx(x, 0); a1 += (w) * b2fx(x, 1); \
    a2 += (w) * b2fx(x, 2); a3 += (w) * b2fx(x, 3); \
    a4 += (w) * b2fx(x, 4); a5 += (w) * b2fx(x, 5); \
    a6 += (w) * b2fx(x, 6); a7 += (w) * b2fx(x, 7);

// ======================= input projection, F=64 (MFMA) =======================
// out[i,j] = x[i,:] . W[:,j] + b[j]  (no relu). A = x (f32 -> bf16, swizzled
// [64][64] LDS tile), B = Win register fragments, K=64. Block covers 512 rows.
__global__ __launch_bounds__(256)
void proj64_mfma_kernel(const float* __restrict__ x, const float* __restrict__ W,
                        const float* __restrict__ b, bf16* __restrict__ out, int n) {
    __shared__ __align__(16) short sP[64 * 64];   // 8 KB
    int tid = threadIdx.x;
    int lane = tid & 63, w = tid >> 6;
    int lm = lane & 15, lq = lane >> 4;

    bf16x8 wc[4][2];
    float bv[4];
#pragma unroll
    for (int ct = 0; ct < 4; ++ct) {
        int colc = ct * 16 + lm;
        wc[ct][0] = load_bfrag(W, lq * 8, colc);
        wc[ct][1] = load_bfrag(W, 32 + lq * 8, colc);
        bv[ct] = b[colc];
    }

    const float4* x4 = (const float4*)x;
    for (int g = 0; g < 8; ++g) {
        int row0 = blockIdx.x * 512 + g * 64;
        if (row0 >= n) break;
        __syncthreads();
        // stage 64 rows of x: f32 float4 -> 8B bf16 granule, swizzled
#pragma unroll
        for (int i = 0; i < 4; ++i) {
            int idx = tid + i * 256;             // 0..1023
            int row = idx >> 4, g4 = idx & 15;   // 16 float4-granules per row
            int grow = row0 + row;
            float4 v = make_float4(0.f, 0.f, 0.f, 0.f);
            if (grow < n) v = x4[(size_t)grow * 16 + g4];
            ushort4 p;
            p.x = f2bb(v.x); p.y = f2bb(v.y); p.z = f2bb(v.z); p.w = f2bb(v.w);
            *(ushort4*)((char*)sP + swzH(row, g4 * 8)) = p;
        }
        __syncthreads();

        int arow = w * 16 + lm;
        bf16x8 a0 = *(const bf16x8*)((char*)sP + swzH(arow, lq * 16));
        bf16x8 a1 = *(const bf16x8*)((char*)sP + swzH(arow, 64 + lq * 16));
#pragma unroll
        for (int ct = 0; ct < 4; ++ct) {
            f32x4 acc = {0.f, 0.f, 0.f, 0.f};
            acc = mfma16(a0, wc[ct][0], acc);
            acc = mfma16(a1, wc[ct][1], acc);
            int colc = ct * 16 + lm;
#pragma unroll
            for (int r = 0; r < 4; ++r) {
                int grow = row0 + w * 16 + lq * 4 + r;
                if (grow < n)
                    out[(size_t)grow * 64 + colc] = f2b(acc[r] + bv[ct]);
            }
        }
    }
}

// ======================= FUSED gather + SAGE epilogue (MFMA) =======================
// out[i,j] = relu( mean_i . Wl[:,j] + bl[j] + xd[i,:] . Wr[:,j] ),
//   mean_i = (1/max(deg_i,1)) * sum_{e in CSR row i} hsrc[col[e], :]
// The gather is computed DIRECTLY into the swizzled LDS A-tile (no mean buffer
// in HBM): per 64-row group, 2 passes x 32 rows, 8 lanes/row, 8 features/lane,
// 16B bf16x8 loads, chunk-of-8 clamped indices + {0,1} weights (bit-identical
// to the standalone round-7 gather). Then one K=128 MFMA GEMM with
// A = [mean | xd], B = [Wl ; Wr] in register fragments. NOT in-place: caller
// ping-pongs buffers (gather reads hsrc globally while outb is written).
// HEAD: t2 restaged bf16 wave-locally into sH, K=64 MFMA GEMM, 16-lane
// shfl_xor reduce for the 64->2 contraction.
template<bool HEAD>
__global__ __launch_bounds__(256, 2)
void sage_fused_kernel(const bf16* __restrict__ hsrc, const int* __restrict__ rowptr,
                       const int* __restrict__ deg, const int* __restrict__ col,
                       const bf16* __restrict__ xd,
                       const float* __restrict__ Wl, const float* __restrict__ bl,
                       const float* __restrict__ Wr,
                       float* __restrict__ outf, bf16* __restrict__ outb,
                       const float* __restrict__ Wh1, const float* __restrict__ bh1,
                       const float* __restrict__ Wh2, const float* __restrict__ bh2,
                       float* __restrict__ logits, int n) {
    __shared__ __align__(16) short sA[64 * 128];              // 16 KB
    __shared__ __align__(16) short sH[HEAD ? 64 * 64 : 8];    // 8 KB (HEAD)
    int tid = threadIdx.x;
    int lane = tid & 63, w = tid >> 6;
    int lm = lane & 15, lq = lane >> 4;

    // --- weight fragments: once per block, held in registers ---
    bf16x8 wc[4][4];   // [col-tile][k-step]; ks 0,1 = Wl(k0=0,32), ks 2,3 = Wr
    bf16x8 wh[4][2];
    float blv[4], h1v[4], w2a[4], w2b[4];
#pragma unroll
    for (int ct = 0; ct < 4; ++ct) {
        int colc = ct * 16 + lm;
        wc[ct][0] = load_bfrag(Wl, lq * 8, colc);
        wc[ct][1] = load_bfrag(Wl, 32 + lq * 8, colc);
        wc[ct][2] = load_bfrag(Wr, lq * 8, colc);
        wc[ct][3] = load_bfrag(Wr, 32 + lq * 8, colc);
        blv[ct] = bl[colc];
        if (HEAD) {
            wh[ct][0] = load_bfrag(Wh1, lq * 8, colc);
            wh[ct][1] = load_bfrag(Wh1, 32 + lq * 8, colc);
            h1v[ct] = bh1[colc];
            w2a[ct] = Wh2[colc * 2 + 0];
            w2b[ct] = Wh2[colc * 2 + 1];
        }
    }
    float b20 = 0.f, b21 = 0.f;
    if (HEAD) { b20 = bh2[0]; b21 = bh2[1]; }

    const bf16x8* xd8 = (const bf16x8*)xd;

    for (int g = 0; g < 8; ++g) {
        int row0 = blockIdx.x * 512 + g * 64;
        if (row0 >= n) break;
        __syncthreads();   // protect sA reuse (prev group's fragment reads done)
        // --- stage xd -> cols 64..127 (16B granules, 2/thread) ---
#pragma unroll
        for (int i = 0; i < 2; ++i) {
            int idx = tid + i * 256;             // 0..511
            int row = idx >> 3, c8 = idx & 7;
            int grow = row0 + row;
            bf16x8 u;
#pragma unroll
            for (int j = 0; j < 8; ++j) u[j] = 0;
            if (grow < n) u = xd8[(size_t)grow * 8 + c8];
            *(bf16x8*)((char*)sA + swzA(row, 128 + c8 * 16)) = u;
        }
        // --- gather mean -> cols 0..63 (2 passes x 32 rows; 8 lanes/row) ---
#pragma unroll
        for (int p = 0; p < 2; ++p) {
            int lrow = p * 32 + (tid >> 3);
            int grow = row0 + lrow;
            int fg = tid & 7;
            float a0 = 0.f, a1 = 0.f, a2 = 0.f, a3 = 0.f;
            float a4 = 0.f, a5 = 0.f, a6 = 0.f, a7 = 0.f;
            float dd = 1.f;
            if (grow < n) {
                int base = rowptr[grow];
                int d = deg[grow];
                int lasto = (d > 0) ? d - 1 : 0;
                for (int e0 = 0; e0 < d; e0 += 8) {
                    int o1 = (e0 + 1 < d) ? e0 + 1 : lasto;
                    int o2 = (e0 + 2 < d) ? e0 + 2 : lasto;
                    int o3 = (e0 + 3 < d) ? e0 + 3 : lasto;
                    int o4 = (e0 + 4 < d) ? e0 + 4 : lasto;
                    int o5 = (e0 + 5 < d) ? e0 + 5 : lasto;
                    int o6 = (e0 + 6 < d) ? e0 + 6 : lasto;
                    int o7 = (e0 + 7 < d) ? e0 + 7 : lasto;
                    int s0 = col[base + e0], s1 = col[base + o1];
                    int s2 = col[base + o2], s3 = col[base + o3];
                    int s4 = col[base + o4], s5 = col[base + o5];
                    int s6 = col[base + o6], s7 = col[base + o7];
                    bf16x8 x0 = *(const bf16x8*)(hsrc + ((size_t)s0 << 6) + (fg << 3));
                    bf16x8 x1 = *(const bf16x8*)(hsrc + ((size_t)s1 << 6) + (fg << 3));
                    bf16x8 x2 = *(const bf16x8*)(hsrc + ((size_t)s2 << 6) + (fg << 3));
                    bf16x8 x3 = *(const bf16x8*)(hsrc + ((size_t)s3 << 6) + (fg << 3));
                    bf16x8 x4 = *(const bf16x8*)(hsrc + ((size_t)s4 << 6) + (fg << 3));
                    bf16x8 x5 = *(const bf16x8*)(hsrc + ((size_t)s5 << 6) + (fg << 3));
                    bf16x8 x6 = *(const bf16x8*)(hsrc + ((size_t)s6 << 6) + (fg << 3));
                    bf16x8 x7 = *(const bf16x8*)(hsrc + ((size_t)s7 << 6) + (fg << 3));
                    float w1 = (e0 + 1 < d) ? 1.f : 0.f;
                    float w2 = (e0 + 2 < d) ? 1.f : 0.f;
                    float w3 = (e0 + 3 < d) ? 1.f : 0.f;
                    float w4 = (e0 + 4 < d) ? 1.f : 0.f;
                    float w5 = (e0 + 5 < d) ? 1.f : 0.f;
                    float w6 = (e0 + 6 < d) ? 1.f : 0.f;
                    float w7 = (e0 + 7 < d) ? 1.f : 0.f;
                    GM_ACC(x0, 1.f)
                    GM_ACC(x1, w1)
                    GM_ACC(x2, w2)
                    GM_ACC(x3, w3)
                    GM_ACC(x4, w4)
                    GM_ACC(x5, w5)
                    GM_ACC(x6, w6)
                    GM_ACC(x7, w7)
                }
                dd = fmaxf((float)d, 1.f);
            }
            bf16x8 o;
            o[0] = (short)f2bb(a0 / dd); o[1] = (short)f2bb(a1 / dd);
            o[2] = (short)f2bb(a2 / dd); o[3] = (short)f2bb(a3 / dd);
            o[4] = (short)f2bb(a4 / dd); o[5] = (short)f2bb(a5 / dd);
            o[6] = (short)f2bb(a6 / dd); o[7] = (short)f2bb(a7 / dd);
            int fgb = (tid & 7) << 4;
            *(bf16x8*)((char*)sA + swzA(lrow, fgb)) = o;
        }
        __syncthreads();

        // --- compute: wave w owns rows w*16..w*16+15 ---
        int arow = w * 16 + lm;
        bf16x8 a0 = *(const bf16x8*)((char*)sA + swzA(arow, lq * 16));
        bf16x8 a1 = *(const bf16x8*)((char*)sA + swzA(arow, 64 + lq * 16));
        bf16x8 a2 = *(const bf16x8*)((char*)sA + swzA(arow, 128 + lq * 16));
        bf16x8 a3 = *(const bf16x8*)((char*)sA + swzA(arow, 192 + lq * 16));
#pragma unroll
        for (int ct = 0; ct < 4; ++ct) {
            f32x4 acc = {0.f, 0.f, 0.f, 0.f};
            acc = mfma16(a0, wc[ct][0], acc);
            acc = mfma16(a1, wc[ct][1], acc);
            acc = mfma16(a2, wc[ct][2], acc);
            acc = mfma16(a3, wc[ct][3], acc);
            int colc = ct * 16 + lm;
#pragma unroll
            for (int r = 0; r < 4; ++r) {
                int lrow = w * 16 + lq * 4 + r;
                int grow = row0 + lrow;
                float v = fmaxf(acc[r] + blv[ct], 0.f);
                if (grow < n) {
                    if (outf) outf[(size_t)grow * 64 + colc] = v;
                    if (outb) outb[(size_t)grow * 64 + colc] = f2b(v);
                }
                if (HEAD)   // wave-local restage; same wave reads below
                    *(short*)((char*)sH + swzH(lrow, colc * 2)) = (short)f2bb(v);
            }
        }
        if (HEAD) {
            bf16x8 h0 = *(const bf16x8*)((char*)sH + swzH(arow, lq * 16));
            bf16x8 h1 = *(const bf16x8*)((char*)sH + swzH(arow, 64 + lq * 16));
            float qa0 = 0.f, qa1 = 0.f, qa2 = 0.f, qa3 = 0.f;
            float qb0 = 0.f, qb1 = 0.f, qb2 = 0.f, qb3 = 0.f;
#pragma unroll
            for (int ct = 0; ct < 4; ++ct) {
                f32x4 acc = {0.f, 0.f, 0.f, 0.f};
                acc = mfma16(h0, wh[ct][0], acc);
                acc = mfma16(h1, wh[ct][1], acc);
                float hb = h1v[ct];
                float h_0 = fmaxf(acc[0] + hb, 0.f);
                float h_1 = fmaxf(acc[1] + hb, 0.f);
                float h_2 = fmaxf(acc[2] + hb, 0.f);
                float h_3 = fmaxf(acc[3] + hb, 0.f);
                qa0 += h_0 * w2a[ct]; qb0 += h_0 * w2b[ct];
                qa1 += h_1 * w2a[ct]; qb1 += h_1 * w2b[ct];
                qa2 += h_2 * w2a[ct]; qb2 += h_2 * w2b[ct];
                qa3 += h_3 * w2a[ct]; qb3 += h_3 * w2b[ct];
            }
#pragma unroll
            for (int m = 8; m; m >>= 1) {   // reduce over the 16-lane quad
                qa0 += __shfl_xor(qa0, m); qb0 += __shfl_xor(qb0, m);
                qa1 += __shfl_xor(qa1, m); qb1 += __shfl_xor(qb1, m);
                qa2 += __shfl_xor(qa2, m); qb2 += __shfl_xor(qb2, m);
                qa3 += __shfl_xor(qa3, m); qb3 += __shfl_xor(qb3, m);
            }
            int rowb = row0 + w * 16 + lq * 4;
            if (lm == 0) {
                if (rowb + 0 < n) { logits[(size_t)(rowb + 0) * 2 + 0] = qa0 + b20;
                                    logits[(size_t)(rowb + 0) * 2 + 1] = qb0 + b21; }
                if (rowb + 1 < n) { logits[(size_t)(rowb + 1) * 2 + 0] = qa1 + b20;
                                    logits[(size_t)(rowb + 1) * 2 + 1] = qb1 + b21; }
                if (rowb + 2 < n) { logits[(size_t)(rowb + 2) * 2 + 0] = qa2 + b20;
                                    logits[(size_t)(rowb + 2) * 2 + 1] = qb2 + b21; }
                if (rowb + 3 < n) { logits[(size_t)(rowb + 3) * 2 + 0] = qa3 + b20;
                                    logits[(size_t)(rowb + 3) * 2 + 1] = qb3 + b21; }
            }
        }
    }
}

// out[i,j] = sum_k x[i,k]*W[k,j] + b[j]   (x,W,b f32 -> out bf16), no relu
// (VALU version, used only for the small F=32 projection)
template<int F>
__global__ void proj_kernel(const float* __restrict__ x, const float* __restrict__ W,
                            const float* __restrict__ b, bf16* __restrict__ out, int n) {
    __shared__ float sW[F][64];
    __shared__ float sb[64];
    __shared__ float sx[16][F];
    int tid = threadIdx.x;
    for (int idx = tid; idx < F * 16; idx += 256)
        ((float4*)sW)[idx] = ((const float4*)W)[idx];
    if (tid < 64) sb[tid] = b[tid];
    int base = blockIdx.x * 64;
    int w = tid >> 6, j = tid & 63;
    int lw = w * 4;
    for (int g = 0; g < 4; ++g) {
        int row0 = base + g * 16;
        __syncthreads();
        for (int idx = tid; idx < 4 * F; idx += 256) {
            int rr = idx / (F / 4), c4 = idx - rr * (F / 4);
            int row = row0 + rr;
            float4 v = (row < n) ? ((const float4*)x)[(size_t)row * (F / 4) + c4]
                                 : make_float4(0.f, 0.f, 0.f, 0.f);
            *(float4*)&sx[rr][c4 * 4] = v;
        }
        __syncthreads();
        float a0 = sb[j], a1 = sb[j], a2 = sb[j], a3 = sb[j];
#pragma unroll 2
        for (int k = 0; k < F; k += 4) {
            float w0 = sW[k][j], w1 = sW[k + 1][j], w2 = sW[k + 2][j], w3 = sW[k + 3][j];
            float4 m0 = *(const float4*)&sx[lw + 0][k];
            float4 m1 = *(const float4*)&sx[lw + 1][k];
            float4 m2 = *(const float4*)&sx[lw + 2][k];
            float4 m3 = *(const float4*)&sx[lw + 3][k];
            a0 += m0.x * w0 + m0.y * w1 + m0.z * w2 + m0.w * w3;
            a1 += m1.x * w0 + m1.y * w1 + m1.z * w2 + m1.w * w3;
            a2 += m2.x * w0 + m2.y * w1 + m2.z * w2 + m2.w * w3;
            a3 += m3.x * w0 + m3.y * w1 + m3.z * w2 + m3.w * w3;
        }
        int r0 = row0 + lw;
        if (r0 + 0 < n) out[(size_t)(r0 + 0) * 64 + j] = f2b(a0);
        if (r0 + 1 < n) out[(size_t)(r0 + 1) * 64 + j] = f2b(a1);
        if (r0 + 2 < n) out[(size_t)(r0 + 2) * 64 + j] = f2b(a2);
        if (r0 + 3 < n) out[(size_t)(r0 + 3) * 64 + j] = f2b(a3);
    }
}

extern "C" void kernel_launch(void* const* d_in, const int* in_sizes, int n_in,
                              void* d_out, int out_size, void* d_ws, size_t ws_size,
                              hipStream_t stream) {
    const float* x_tx   = (const float*)d_in[0];
    const float* x_w    = (const float*)d_in[1];
    const int*   src_tw = (const int*)d_in[2];
    const int*   dst_tw = (const int*)d_in[3];
    const int*   src_wt = (const int*)d_in[4];
    const int*   dst_wt = (const int*)d_in[5];
    const float* Win_tx = (const float*)d_in[6];
    const float* bin_tx = (const float*)d_in[7];
    const float* Win_w  = (const float*)d_in[8];
    const float* bin_w  = (const float*)d_in[9];
    const float* Wl1_tw = (const float*)d_in[10];
    const float* bl1_tw = (const float*)d_in[11];
    const float* Wr1_tw = (const float*)d_in[12];
    const float* Wl1_wt = (const float*)d_in[13];
    const float* bl1_wt = (const float*)d_in[14];
    const float* Wr1_wt = (const float*)d_in[15];
    const float* Wl2_tw = (const float*)d_in[16];
    const float* bl2_tw = (const float*)d_in[17];
    const float* Wr2_tw = (const float*)d_in[18];
    const float* Wl2_wt = (const float*)d_in[19];
    const float* bl2_wt = (const float*)d_in[20];
    const float* Wr2_wt = (const float*)d_in[21];
    const float* Wh1    = (const float*)d_in[22];
    const float* bh1    = (const float*)d_in[23];
    const float* Wh2    = (const float*)d_in[24];
    const float* bh2    = (const float*)d_in[25];

    const int n_tx  = in_sizes[0] / 64;
    const int n_w   = in_sizes[1] / 32;
    const int ne_tw = in_sizes[2];
    const int ne_wt = in_sizes[4];

    // ---- workspace layout (ping-pong feature buffers; ~366 MB) ----
    bf16* A       = (bf16*)d_ws;                          // n_tx*64 bf16: h_tx (conv1 src)
    bf16* B       = A + (size_t)n_tx * 64;                // n_w *64 bf16: h_w  (conv1 src)
    bf16* A2      = B + (size_t)n_w * 64;                 // n_tx*64 bf16: t1 (conv2 src)
    bf16* B2      = A2 + (size_t)n_tx * 64;               // n_w *64 bf16: w1 (conv2 src)
    int*  deg_w   = (int*)(B2 + (size_t)n_w * 64);        // n_w
    int*  deg_tx  = deg_w + n_w;                          // n_tx
    int*  rp_w    = deg_tx + n_tx;                        // n_w
    int*  rp_tx   = rp_w + n_w;                           // n_tx
    int*  cur_w   = rp_tx + n_tx;                         // n_w  (excl scratch, then cursor)
    int*  cur_tx  = cur_w + n_w;                          // n_tx
    int*  col_tw  = cur_tx + n_tx;                        // ne_tw
    int*  col_wt  = col_tw + ne_tw;                       // ne_wt
    int*  part_w  = col_wt + ne_wt;                       // <=4096
    int*  part_tx = part_w + 4096;                        // <=4096

    float* out_logits = (float*)d_out;
    float* out_t2 = out_logits + (size_t)n_tx * 2;
    float* out_w2 = out_t2 + (size_t)n_tx * 64;

    dim3 blk(256);
    int grid_proj_tx = (n_tx + 511) / 512;
    int grid_proj_w  = (n_w + 63) / 64;
    int grid_sage_tx = (n_tx + 511) / 512;
    int grid_sage_w  = (n_w + 511) / 512;
    int grid_e_tw    = (ne_tw + 255) / 256;
    int grid_e_wt    = (ne_wt + 255) / 256;
    int np_w  = (n_w + 1023) / 1024;
    int np_tx = (n_tx + 1023) / 1024;

    // ---- CSR build (graph static: reused by conv1 AND conv2) ----
    hipMemsetAsync(deg_w, 0, (size_t)n_w * sizeof(int), stream);
    hipMemsetAsync(deg_tx, 0, (size_t)n_tx * sizeof(int), stream);
    count_int_kernel<<<grid_e_tw, blk, 0, stream>>>(dst_tw, deg_w, ne_tw);
    count_int_kernel<<<grid_e_wt, blk, 0, stream>>>(dst_wt, deg_tx, ne_wt);
    scan1_kernel<<<np_w, blk, 0, stream>>>(deg_w, cur_w, part_w, n_w);
    scan2_kernel<<<1, blk, 0, stream>>>(part_w, np_w);
    scan3_kernel<<<(n_w + 255) / 256, blk, 0, stream>>>(cur_w, part_w, rp_w, cur_w, n_w);
    scan1_kernel<<<np_tx, blk, 0, stream>>>(deg_tx, cur_tx, part_tx, n_tx);
    scan2_kernel<<<1, blk, 0, stream>>>(part_tx, np_tx);
    scan3_kernel<<<(n_tx + 255) / 256, blk, 0, stream>>>(cur_tx, part_tx, rp_tx, cur_tx, n_tx);
    scatter_kernel<<<grid_e_tw, blk, 0, stream>>>(src_tw, dst_tw, cur_w, col_tw, ne_tw);
    scatter_kernel<<<grid_e_wt, blk, 0, stream>>>(src_wt, dst_wt, cur_tx, col_wt, ne_wt);

    // ---- input projections ----
    proj64_mfma_kernel<<<grid_proj_tx, blk, 0, stream>>>(x_tx, Win_tx, bin_tx, A, n_tx);
    proj_kernel<32><<<grid_proj_w, blk, 0, stream>>>(x_w, Win_w, bin_w, B, n_w);

    // ---- conv1 (fused gather+GEMM, ping-pong A,B -> A2,B2) ----
    sage_fused_kernel<false><<<grid_sage_w, blk, 0, stream>>>(
        A, rp_w, deg_w, col_tw, B, Wl1_tw, bl1_tw, Wr1_tw,
        nullptr, B2, nullptr, nullptr, nullptr, nullptr, nullptr, n_w);   // w1 -> B2
    sage_fused_kernel<false><<<grid_sage_tx, blk, 0, stream>>>(
        B, rp_tx, deg_tx, col_wt, A, Wl1_wt, bl1_wt, Wr1_wt,
        nullptr, A2, nullptr, nullptr, nullptr, nullptr, nullptr, n_tx);  // t1 -> A2

    // ---- conv2 (fused, reads A2/B2, writes f32 outputs) ----
    sage_fused_kernel<false><<<grid_sage_w, blk, 0, stream>>>(
        A2, rp_w, deg_w, col_tw, B2, Wl2_tw, bl2_tw, Wr2_tw,
        out_w2, nullptr, nullptr, nullptr, nullptr, nullptr, nullptr, n_w);   // w2 -> f32 out
    sage_fused_kernel<true><<<grid_sage_tx, blk, 0, stream>>>(
        B2, rp_tx, deg_tx, col_wt, A2, Wl2_wt, bl2_wt, Wr2_wt,
        out_t2, nullptr, Wh1, bh1, Wh2, bh2, out_logits, n_tx);               // t2 + logits
}

// Round 9
// 1639.142 us; speedup vs baseline: 1.0774x; 1.0774x over previous
//
#include <hip/hip_runtime.h>
#include <hip/hip_bf16.h>

typedef __hip_bfloat16 bf16;
typedef __attribute__((ext_vector_type(8))) short bf16x8;   // 8 bf16 = 4 VGPR
typedef __attribute__((ext_vector_type(4))) float f32x4;    // MFMA accumulator

__device__ __forceinline__ float b2f(bf16 v) { return __bfloat162float(v); }
__device__ __forceinline__ bf16 f2b(float v) { return __float2bfloat16(v); }
__device__ __forceinline__ unsigned short f2bb(float v) {   // RNE f32->bf16 bits
    unsigned int u = __float_as_uint(v);
    u += 0x7fffu + ((u >> 16) & 1u);
    return (unsigned short)(u >> 16);
}
// bf16x8 element k (compile-time k) -> f32 via bit shift
__device__ __forceinline__ float b2fx(bf16x8 v, int k) {
    return __uint_as_float(((unsigned int)(unsigned short)v[k]) << 16);
}

__device__ __forceinline__ f32x4 mfma16(bf16x8 a, bf16x8 b, f32x4 c) {
    return __builtin_amdgcn_mfma_f32_16x16x32_bf16(a, b, c, 0, 0, 0);
}

// Gather a B-fragment: rows k0..k0+7 of column col from row-major W[64][64] f32.
__device__ __forceinline__ bf16x8 load_bfrag(const float* __restrict__ W, int k0, int col) {
    bf16x8 f;
#pragma unroll
    for (int j = 0; j < 8; ++j)
        f[j] = (short)f2bb(W[(size_t)(k0 + j) * 64 + col]);
    return f;
}

// Swizzled byte offset for the HEAD restage tile ([64][64 bf16], 128B rows).
__device__ __forceinline__ int swzH(int row, int b) {
    return row * 128 + (b ^ ((row & 7) << 4));
}

// ======================= CSR build =======================
__global__ void count_int_kernel(const int* __restrict__ dst, int* __restrict__ deg, int ne) {
    int e = blockIdx.x * 256 + threadIdx.x;
    if (e < ne) atomicAdd(&deg[dst[e]], 1);
}

// block-local exclusive scan over 1024 elems (256 thr x 4); writes block totals
__global__ void scan1_kernel(const int* __restrict__ deg, int* __restrict__ excl,
                             int* __restrict__ partial, int n) {
    __shared__ int sT[256];
    int tid = threadIdx.x;
    int base = blockIdx.x * 1024 + tid * 4;
    int v0 = (base + 0 < n) ? deg[base + 0] : 0;
    int v1 = (base + 1 < n) ? deg[base + 1] : 0;
    int v2 = (base + 2 < n) ? deg[base + 2] : 0;
    int v3 = (base + 3 < n) ? deg[base + 3] : 0;
    int t = v0 + v1 + v2 + v3;
    sT[tid] = t;
    __syncthreads();
    for (int off = 1; off < 256; off <<= 1) {   // Hillis-Steele inclusive
        int x = (tid >= off) ? sT[tid - off] : 0;
        __syncthreads();
        sT[tid] += x;
        __syncthreads();
    }
    int et = sT[tid] - t;
    if (tid == 255) partial[blockIdx.x] = sT[255];
    if (base + 0 < n) excl[base + 0] = et;
    if (base + 1 < n) excl[base + 1] = et + v0;
    if (base + 2 < n) excl[base + 2] = et + v0 + v1;
    if (base + 3 < n) excl[base + 3] = et + v0 + v1 + v2;
}

// single-block exclusive scan of the partials (np <= a few thousand)
__global__ void scan2_kernel(int* __restrict__ partial, int np) {
    __shared__ int sT[256];
    __shared__ int carry;
    int tid = threadIdx.x;
    if (tid == 0) carry = 0;
    __syncthreads();
    for (int c = 0; c < np; c += 256) {
        int i = c + tid;
        int v = (i < np) ? partial[i] : 0;
        sT[tid] = v;
        __syncthreads();
        for (int off = 1; off < 256; off <<= 1) {
            int x = (tid >= off) ? sT[tid - off] : 0;
            __syncthreads();
            sT[tid] += x;
            __syncthreads();
        }
        int incl = sT[tid];
        int total = sT[255];
        if (i < np) partial[i] = carry + incl - v;
        __syncthreads();
        if (tid == 0) carry += total;
        __syncthreads();
    }
}

// rowptr[i] = cursor[i] = excl[i] + partial[i>>10]  (cursor may alias excl)
__global__ void scan3_kernel(const int* __restrict__ excl, const int* __restrict__ partial,
                             int* __restrict__ rowptr, int* __restrict__ cursor, int n) {
    int i = blockIdx.x * 256 + threadIdx.x;
    if (i < n) {
        int v = excl[i] + partial[i >> 10];
        rowptr[i] = v;
        cursor[i] = v;
    }
}

__global__ void scatter_kernel(const int* __restrict__ src, const int* __restrict__ dst,
                               int* __restrict__ cursor, int* __restrict__ col, int ne) {
    int e = blockIdx.x * 256 + threadIdx.x;
    if (e < ne) {
        int p = atomicAdd(&cursor[dst[e]], 1);
        col[p] = src[e];
    }
}

// ======================= gather mean (round-7 proven) =======================
// mean[i,:] = (1/max(deg_i,1)) * sum_{e in row i} h[col[e], :]   (bf16 out)
// Wave repack: 8 rows/wave, 8 lanes/row, 8 features/lane; 16B bf16x8 loads;
// chunk-of-8 clamped indices + {0,1} weights (bit-identical summation order).
#define GM_ACC(x, w) \
    a0 += (w) * b2fx(x, 0); a1 += (w) * b2fx(x, 1); \
    a2 += (w) * b2fx(x, 2); a3 += (w) * b2fx(x, 3); \
    a4 += (w) * b2fx(x, 4); a5 += (w) * b2fx(x, 5); \
    a6 += (w) * b2fx(x, 6); a7 += (w) * b2fx(x, 7);

__global__ __launch_bounds__(256)
void gather_mean_kernel(const bf16* __restrict__ h, const int* __restrict__ rowptr,
                        const int* __restrict__ deg, const int* __restrict__ col,
                        bf16* __restrict__ mean, int n) {
    int tid = threadIdx.x;
    int row = blockIdx.x * 32 + (tid >> 3);   // 32 rows per block, 8 lanes each
    if (row >= n) return;
    int fg = tid & 7;                         // feature octet: cols fg*8..fg*8+7
    int base = rowptr[row];
    int d = deg[row];
    int lasto = (d > 0) ? d - 1 : 0;
    float a0 = 0.f, a1 = 0.f, a2 = 0.f, a3 = 0.f;
    float a4 = 0.f, a5 = 0.f, a6 = 0.f, a7 = 0.f;
    for (int e0 = 0; e0 < d; e0 += 8) {
        int o1 = (e0 + 1 < d) ? e0 + 1 : lasto;
        int o2 = (e0 + 2 < d) ? e0 + 2 : lasto;
        int o3 = (e0 + 3 < d) ? e0 + 3 : lasto;
        int o4 = (e0 + 4 < d) ? e0 + 4 : lasto;
        int o5 = (e0 + 5 < d) ? e0 + 5 : lasto;
        int o6 = (e0 + 6 < d) ? e0 + 6 : lasto;
        int o7 = (e0 + 7 < d) ? e0 + 7 : lasto;
        int s0 = col[base + e0], s1 = col[base + o1];
        int s2 = col[base + o2], s3 = col[base + o3];
        int s4 = col[base + o4], s5 = col[base + o5];
        int s6 = col[base + o6], s7 = col[base + o7];
        bf16x8 x0 = *(const bf16x8*)(h + ((size_t)s0 << 6) + (fg << 3));
        bf16x8 x1 = *(const bf16x8*)(h + ((size_t)s1 << 6) + (fg << 3));
        bf16x8 x2 = *(const bf16x8*)(h + ((size_t)s2 << 6) + (fg << 3));
        bf16x8 x3 = *(const bf16x8*)(h + ((size_t)s3 << 6) + (fg << 3));
        bf16x8 x4 = *(const bf16x8*)(h + ((size_t)s4 << 6) + (fg << 3));
        bf16x8 x5 = *(const bf16x8*)(h + ((size_t)s5 << 6) + (fg << 3));
        bf16x8 x6 = *(const bf16x8*)(h + ((size_t)s6 << 6) + (fg << 3));
        bf16x8 x7 = *(const bf16x8*)(h + ((size_t)s7 << 6) + (fg << 3));
        float w1 = (e0 + 1 < d) ? 1.f : 0.f;
        float w2 = (e0 + 2 < d) ? 1.f : 0.f;
        float w3 = (e0 + 3 < d) ? 1.f : 0.f;
        float w4 = (e0 + 4 < d) ? 1.f : 0.f;
        float w5 = (e0 + 5 < d) ? 1.f : 0.f;
        float w6 = (e0 + 6 < d) ? 1.f : 0.f;
        float w7 = (e0 + 7 < d) ? 1.f : 0.f;
        GM_ACC(x0, 1.f)
        GM_ACC(x1, w1)
        GM_ACC(x2, w2)
        GM_ACC(x3, w3)
        GM_ACC(x4, w4)
        GM_ACC(x5, w5)
        GM_ACC(x6, w6)
        GM_ACC(x7, w7)
    }
    float dd = fmaxf((float)d, 1.f);
    bf16x8 o;
    o[0] = (short)f2bb(a0 / dd); o[1] = (short)f2bb(a1 / dd);
    o[2] = (short)f2bb(a2 / dd); o[3] = (short)f2bb(a3 / dd);
    o[4] = (short)f2bb(a4 / dd); o[5] = (short)f2bb(a5 / dd);
    o[6] = (short)f2bb(a6 / dd); o[7] = (short)f2bb(a7 / dd);
    *(bf16x8*)(mean + ((size_t)row << 6) + (fg << 3)) = o;
}

// ======================= input projection, F=64 (MFMA, LDS-free) ============
// out[i,j] = x[i,:] . W[:,j] + b[j]  (no relu). Each wave owns 16 rows of a
// 64-row group: A-fragments read DIRECTLY from global (row = row0+w*16+lm,
// f32 cols lq*8.., converted to bf16 in registers) — no LDS, no barriers.
// Tail rows clamp the load address to n-1 (writes stay guarded).
__global__ __launch_bounds__(256)
void proj64_mfma_kernel(const float* __restrict__ x, const float* __restrict__ W,
                        const float* __restrict__ b, bf16* __restrict__ out, int n) {
    int tid = threadIdx.x;
    int lane = tid & 63, w = tid >> 6;
    int lm = lane & 15, lq = lane >> 4;

    bf16x8 wc[4][2];
    float bv[4];
#pragma unroll
    for (int ct = 0; ct < 4; ++ct) {
        int colc = ct * 16 + lm;
        wc[ct][0] = load_bfrag(W, lq * 8, colc);
        wc[ct][1] = load_bfrag(W, 32 + lq * 8, colc);
        bv[ct] = b[colc];
    }

    for (int g = 0; g < 8; ++g) {
        int row0 = blockIdx.x * 512 + g * 64;
        if (row0 >= n) break;
        int arow = row0 + w * 16 + lm;
        int ar = (arow < n) ? arow : (n - 1);
        const float* xrow = x + ((size_t)ar << 6);
        float4 p0 = *(const float4*)(xrow + lq * 8);
        float4 p1 = *(const float4*)(xrow + lq * 8 + 4);
        float4 p2 = *(const float4*)(xrow + 32 + lq * 8);
        float4 p3 = *(const float4*)(xrow + 32 + lq * 8 + 4);
        bf16x8 a0, a1;
        a0[0] = (short)f2bb(p0.x); a0[1] = (short)f2bb(p0.y);
        a0[2] = (short)f2bb(p0.z); a0[3] = (short)f2bb(p0.w);
        a0[4] = (short)f2bb(p1.x); a0[5] = (short)f2bb(p1.y);
        a0[6] = (short)f2bb(p1.z); a0[7] = (short)f2bb(p1.w);
        a1[0] = (short)f2bb(p2.x); a1[1] = (short)f2bb(p2.y);
        a1[2] = (short)f2bb(p2.z); a1[3] = (short)f2bb(p2.w);
        a1[4] = (short)f2bb(p3.x); a1[5] = (short)f2bb(p3.y);
        a1[6] = (short)f2bb(p3.z); a1[7] = (short)f2bb(p3.w);
#pragma unroll
        for (int ct = 0; ct < 4; ++ct) {
            f32x4 acc = {0.f, 0.f, 0.f, 0.f};
            acc = mfma16(a0, wc[ct][0], acc);
            acc = mfma16(a1, wc[ct][1], acc);
            int colc = ct * 16 + lm;
#pragma unroll
            for (int r = 0; r < 4; ++r) {
                int grow = row0 + w * 16 + lq * 4 + r;
                if (grow < n)
                    out[(size_t)grow * 64 + colc] = f2b(acc[r] + bv[ct]);
            }
        }
    }
}

// ======================= SAGE epilogue (MFMA, LDS-free) ======================
// out[i,j] = relu( mean[i,:] . Wl[:,j] + bl[j] + xd[i,:] . Wr[:,j] )
// One K=128 GEMM, A = [mean | xd]. KEY: each wave's A-fragments come ONLY from
// its own 16 rows (row0+w*16+lm) and its writes go ONLY to those rows, so the
// fragments load DIRECTLY from global — no LDS A-tile, no __syncthreads.
// In-place outb==xd is safe per-wave: all 4 fragment loads precede all writes
// (data dependency through the MFMA). Tail rows clamp load address to n-1.
// HEAD: t2 restaged bf16 into sH — wave-local rows, per-wave LDS program
// order, still no barriers — then K=64 MFMA GEMM + 16-lane shfl_xor reduce.
template<bool HEAD>
__global__ __launch_bounds__(256, 2)
void sage_mfma_kernel(const bf16* __restrict__ mean, const bf16* __restrict__ xd,
                      const float* __restrict__ Wl, const float* __restrict__ bl,
                      const float* __restrict__ Wr,
                      float* __restrict__ outf, bf16* __restrict__ outb,
                      const float* __restrict__ Wh1, const float* __restrict__ bh1,
                      const float* __restrict__ Wh2, const float* __restrict__ bh2,
                      float* __restrict__ logits, int n) {
    __shared__ __align__(16) short sH[HEAD ? 64 * 64 : 8];    // 8 KB (HEAD only)
    int tid = threadIdx.x;
    int lane = tid & 63, w = tid >> 6;
    int lm = lane & 15, lq = lane >> 4;

    // --- weight fragments: once per block, held in registers ---
    bf16x8 wc[4][4];   // [col-tile][k-step]; ks 0,1 = Wl(k0=0,32), ks 2,3 = Wr
    bf16x8 wh[4][2];
    float blv[4], h1v[4], w2a[4], w2b[4];
#pragma unroll
    for (int ct = 0; ct < 4; ++ct) {
        int colc = ct * 16 + lm;
        wc[ct][0] = load_bfrag(Wl, lq * 8, colc);
        wc[ct][1] = load_bfrag(Wl, 32 + lq * 8, colc);
        wc[ct][2] = load_bfrag(Wr, lq * 8, colc);
        wc[ct][3] = load_bfrag(Wr, 32 + lq * 8, colc);
        blv[ct] = bl[colc];
        if (HEAD) {
            wh[ct][0] = load_bfrag(Wh1, lq * 8, colc);
            wh[ct][1] = load_bfrag(Wh1, 32 + lq * 8, colc);
            h1v[ct] = bh1[colc];
            w2a[ct] = Wh2[colc * 2 + 0];
            w2b[ct] = Wh2[colc * 2 + 1];
        }
    }
    float b20 = 0.f, b21 = 0.f;
    if (HEAD) { b20 = bh2[0]; b21 = bh2[1]; }

    for (int g = 0; g < 8; ++g) {
        int row0 = blockIdx.x * 512 + g * 64;
        if (row0 >= n) break;
        int larow = w * 16 + lm;             // local A-fragment row (0..63)
        int arow = row0 + larow;
        int ar = (arow < n) ? arow : (n - 1);
        const bf16* mrow = mean + ((size_t)ar << 6);
        const bf16* xrow = xd + ((size_t)ar << 6);
        bf16x8 a0 = *(const bf16x8*)(mrow + lq * 8);        // mean k 0..31
        bf16x8 a1 = *(const bf16x8*)(mrow + 32 + lq * 8);   // mean k 32..63
        bf16x8 a2 = *(const bf16x8*)(xrow + lq * 8);        // xd   k 0..31
        bf16x8 a3 = *(const bf16x8*)(xrow + 32 + lq * 8);   // xd   k 32..63
#pragma unroll
        for (int ct = 0; ct < 4; ++ct) {
            f32x4 acc = {0.f, 0.f, 0.f, 0.f};
            acc = mfma16(a0, wc[ct][0], acc);
            acc = mfma16(a1, wc[ct][1], acc);
            acc = mfma16(a2, wc[ct][2], acc);
            acc = mfma16(a3, wc[ct][3], acc);
            int colc = ct * 16 + lm;
#pragma unroll
            for (int r = 0; r < 4; ++r) {
                int lrow = w * 16 + lq * 4 + r;
                int grow = row0 + lrow;
                float v = fmaxf(acc[r] + blv[ct], 0.f);
                if (grow < n) {
                    if (outf) outf[(size_t)grow * 64 + colc] = v;
                    if (outb) outb[(size_t)grow * 64 + colc] = f2b(v);
                }
                if (HEAD)   // wave-local restage; same wave reads below
                    *(short*)((char*)sH + swzH(lrow, colc * 2)) = (short)f2bb(v);
            }
        }
        if (HEAD) {
            bf16x8 h0 = *(const bf16x8*)((char*)sH + swzH(larow, lq * 16));
            bf16x8 h1 = *(const bf16x8*)((char*)sH + swzH(larow, 64 + lq * 16));
            float qa0 = 0.f, qa1 = 0.f, qa2 = 0.f, qa3 = 0.f;
            float qb0 = 0.f, qb1 = 0.f, qb2 = 0.f, qb3 = 0.f;
#pragma unroll
            for (int ct = 0; ct < 4; ++ct) {
                f32x4 acc = {0.f, 0.f, 0.f, 0.f};
                acc = mfma16(h0, wh[ct][0], acc);
                acc = mfma16(h1, wh[ct][1], acc);
                float hb = h1v[ct];
                float h_0 = fmaxf(acc[0] + hb, 0.f);
                float h_1 = fmaxf(acc[1] + hb, 0.f);
                float h_2 = fmaxf(acc[2] + hb, 0.f);
                float h_3 = fmaxf(acc[3] + hb, 0.f);
                qa0 += h_0 * w2a[ct]; qb0 += h_0 * w2b[ct];
                qa1 += h_1 * w2a[ct]; qb1 += h_1 * w2b[ct];
                qa2 += h_2 * w2a[ct]; qb2 += h_2 * w2b[ct];
                qa3 += h_3 * w2a[ct]; qb3 += h_3 * w2b[ct];
            }
#pragma unroll
            for (int m = 8; m; m >>= 1) {   // reduce over the 16-lane quad
                qa0 += __shfl_xor(qa0, m); qb0 += __shfl_xor(qb0, m);
                qa1 += __shfl_xor(qa1, m); qb1 += __shfl_xor(qb1, m);
                qa2 += __shfl_xor(qa2, m); qb2 += __shfl_xor(qb2, m);
                qa3 += __shfl_xor(qa3, m); qb3 += __shfl_xor(qb3, m);
            }
            int rowb = row0 + w * 16 + lq * 4;
            if (lm == 0) {
                if (rowb + 0 < n) { logits[(size_t)(rowb + 0) * 2 + 0] = qa0 + b20;
                                    logits[(size_t)(rowb + 0) * 2 + 1] = qb0 + b21; }
                if (rowb + 1 < n) { logits[(size_t)(rowb + 1) * 2 + 0] = qa1 + b20;
                                    logits[(size_t)(rowb + 1) * 2 + 1] = qb1 + b21; }
                if (rowb + 2 < n) { logits[(size_t)(rowb + 2) * 2 + 0] = qa2 + b20;
                                    logits[(size_t)(rowb + 2) * 2 + 1] = qb2 + b21; }
                if (rowb + 3 < n) { logits[(size_t)(rowb + 3) * 2 + 0] = qa3 + b20;
                                    logits[(size_t)(rowb + 3) * 2 + 1] = qb3 + b21; }
            }
        }
    }
}

// out[i,j] = sum_k x[i,k]*W[k,j] + b[j]   (x,W,b f32 -> out bf16), no relu
// (VALU version, used only for the small F=32 projection)
template<int F>
__global__ void proj_kernel(const float* __restrict__ x, const float* __restrict__ W,
                            const float* __restrict__ b, bf16* __restrict__ out, int n) {
    __shared__ float sW[F][64];
    __shared__ float sb[64];
    __shared__ float sx[16][F];
    int tid = threadIdx.x;
    for (int idx = tid; idx < F * 16; idx += 256)
        ((float4*)sW)[idx] = ((const float4*)W)[idx];
    if (tid < 64) sb[tid] = b[tid];
    int base = blockIdx.x * 64;
    int w = tid >> 6, j = tid & 63;
    int lw = w * 4;
    for (int g = 0; g < 4; ++g) {
        int row0 = base + g * 16;
        __syncthreads();
        for (int idx = tid; idx < 4 * F; idx += 256) {
            int rr = idx / (F / 4), c4 = idx - rr * (F / 4);
            int row = row0 + rr;
            float4 v = (row < n) ? ((const float4*)x)[(size_t)row * (F / 4) + c4]
                                 : make_float4(0.f, 0.f, 0.f, 0.f);
            *(float4*)&sx[rr][c4 * 4] = v;
        }
        __syncthreads();
        float a0 = sb[j], a1 = sb[j], a2 = sb[j], a3 = sb[j];
#pragma unroll 2
        for (int k = 0; k < F; k += 4) {
            float w0 = sW[k][j], w1 = sW[k + 1][j], w2 = sW[k + 2][j], w3 = sW[k + 3][j];
            float4 m0 = *(const float4*)&sx[lw + 0][k];
            float4 m1 = *(const float4*)&sx[lw + 1][k];
            float4 m2 = *(const float4*)&sx[lw + 2][k];
            float4 m3 = *(const float4*)&sx[lw + 3][k];
            a0 += m0.x * w0 + m0.y * w1 + m0.z * w2 + m0.w * w3;
            a1 += m1.x * w0 + m1.y * w1 + m1.z * w2 + m1.w * w3;
            a2 += m2.x * w0 + m2.y * w1 + m2.z * w2 + m2.w * w3;
            a3 += m3.x * w0 + m3.y * w1 + m3.z * w2 + m3.w * w3;
        }
        int r0 = row0 + lw;
        if (r0 + 0 < n) out[(size_t)(r0 + 0) * 64 + j] = f2b(a0);
        if (r0 + 1 < n) out[(size_t)(r0 + 1) * 64 + j] = f2b(a1);
        if (r0 + 2 < n) out[(size_t)(r0 + 2) * 64 + j] = f2b(a2);
        if (r0 + 3 < n) out[(size_t)(r0 + 3) * 64 + j] = f2b(a3);
    }
}

extern "C" void kernel_launch(void* const* d_in, const int* in_sizes, int n_in,
                              void* d_out, int out_size, void* d_ws, size_t ws_size,
                              hipStream_t stream) {
    const float* x_tx   = (const float*)d_in[0];
    const float* x_w    = (const float*)d_in[1];
    const int*   src_tw = (const int*)d_in[2];
    const int*   dst_tw = (const int*)d_in[3];
    const int*   src_wt = (const int*)d_in[4];
    const int*   dst_wt = (const int*)d_in[5];
    const float* Win_tx = (const float*)d_in[6];
    const float* bin_tx = (const float*)d_in[7];
    const float* Win_w  = (const float*)d_in[8];
    const float* bin_w  = (const float*)d_in[9];
    const float* Wl1_tw = (const float*)d_in[10];
    const float* bl1_tw = (const float*)d_in[11];
    const float* Wr1_tw = (const float*)d_in[12];
    const float* Wl1_wt = (const float*)d_in[13];
    const float* bl1_wt = (const float*)d_in[14];
    const float* Wr1_wt = (const float*)d_in[15];
    const float* Wl2_tw = (const float*)d_in[16];
    const float* bl2_tw = (const float*)d_in[17];
    const float* Wr2_tw = (const float*)d_in[18];
    const float* Wl2_wt = (const float*)d_in[19];
    const float* bl2_wt = (const float*)d_in[20];
    const float* Wr2_wt = (const float*)d_in[21];
    const float* Wh1    = (const float*)d_in[22];
    const float* bh1    = (const float*)d_in[23];
    const float* Wh2    = (const float*)d_in[24];
    const float* bh2    = (const float*)d_in[25];

    const int n_tx  = in_sizes[0] / 64;
    const int n_w   = in_sizes[1] / 32;
    const int ne_tw = in_sizes[2];
    const int ne_wt = in_sizes[4];

    // ---- workspace layout (~351 MB) ----
    bf16* mean_tx = (bf16*)d_ws;                          // n_tx*64 bf16 (128 MB)
    bf16* mean_w  = mean_tx + (size_t)n_tx * 64;          // n_w *64 bf16 ( 32 MB)
    bf16* A       = mean_w + (size_t)n_w * 64;            // n_tx*64 bf16: h_tx->t1 (in-place)
    bf16* B       = A + (size_t)n_tx * 64;                // n_w *64 bf16: h_w ->w1 (in-place)
    int*  deg_w   = (int*)(B + (size_t)n_w * 64);         // n_w
    int*  deg_tx  = deg_w + n_w;                          // n_tx
    int*  rp_w    = deg_tx + n_tx;                        // n_w
    int*  rp_tx   = rp_w + n_w;                           // n_tx
    int*  cur_w   = rp_tx + n_tx;                         // n_w  (excl scratch, then cursor)
    int*  cur_tx  = cur_w + n_w;                          // n_tx
    int*  col_tw  = cur_tx + n_tx;                        // ne_tw
    int*  col_wt  = col_tw + ne_tw;                       // ne_wt
    int*  part_w  = col_wt + ne_wt;                       // <=4096
    int*  part_tx = part_w + 4096;                        // <=4096

    float* out_logits = (float*)d_out;
    float* out_t2 = out_logits + (size_t)n_tx * 2;
    float* out_w2 = out_t2 + (size_t)n_tx * 64;

    dim3 blk(256);
    int grid_proj_tx = (n_tx + 511) / 512;
    int grid_proj_w  = (n_w + 63) / 64;
    int grid_sage_tx = (n_tx + 511) / 512;
    int grid_sage_w  = (n_w + 511) / 512;
    int grid_e_tw    = (ne_tw + 255) / 256;
    int grid_e_wt    = (ne_wt + 255) / 256;
    int grid_g_tx    = (n_tx + 31) / 32;
    int grid_g_w     = (n_w + 31) / 32;
    int np_w  = (n_w + 1023) / 1024;
    int np_tx = (n_tx + 1023) / 1024;

    // ---- CSR build (graph static: reused by conv1 AND conv2) ----
    hipMemsetAsync(deg_w, 0, (size_t)n_w * sizeof(int), stream);
    hipMemsetAsync(deg_tx, 0, (size_t)n_tx * sizeof(int), stream);
    count_int_kernel<<<grid_e_tw, blk, 0, stream>>>(dst_tw, deg_w, ne_tw);
    count_int_kernel<<<grid_e_wt, blk, 0, stream>>>(dst_wt, deg_tx, ne_wt);
    scan1_kernel<<<np_w, blk, 0, stream>>>(deg_w, cur_w, part_w, n_w);
    scan2_kernel<<<1, blk, 0, stream>>>(part_w, np_w);
    scan3_kernel<<<(n_w + 255) / 256, blk, 0, stream>>>(cur_w, part_w, rp_w, cur_w, n_w);
    scan1_kernel<<<np_tx, blk, 0, stream>>>(deg_tx, cur_tx, part_tx, n_tx);
    scan2_kernel<<<1, blk, 0, stream>>>(part_tx, np_tx);
    scan3_kernel<<<(n_tx + 255) / 256, blk, 0, stream>>>(cur_tx, part_tx, rp_tx, cur_tx, n_tx);
    scatter_kernel<<<grid_e_tw, blk, 0, stream>>>(src_tw, dst_tw, cur_w, col_tw, ne_tw);
    scatter_kernel<<<grid_e_wt, blk, 0, stream>>>(src_wt, dst_wt, cur_tx, col_wt, ne_wt);

    // ---- input projections ----
    proj64_mfma_kernel<<<grid_proj_tx, blk, 0, stream>>>(x_tx, Win_tx, bin_tx, A, n_tx);
    proj_kernel<32><<<grid_proj_w, blk, 0, stream>>>(x_w, Win_w, bin_w, B, n_w);

    // ---- conv1: gather both means (from h_tx=A, h_w=B), then both epilogues ----
    gather_mean_kernel<<<grid_g_w, blk, 0, stream>>>(A, rp_w, deg_w, col_tw, mean_w, n_w);
    gather_mean_kernel<<<grid_g_tx, blk, 0, stream>>>(B, rp_tx, deg_tx, col_wt, mean_tx, n_tx);
    sage_mfma_kernel<false><<<grid_sage_w, blk, 0, stream>>>(
        mean_w, B, Wl1_tw, bl1_tw, Wr1_tw,
        nullptr, B, nullptr, nullptr, nullptr, nullptr, nullptr, n_w);    // w1 (in-place B)
    sage_mfma_kernel<false><<<grid_sage_tx, blk, 0, stream>>>(
        mean_tx, A, Wl1_wt, bl1_wt, Wr1_wt,
        nullptr, A, nullptr, nullptr, nullptr, nullptr, nullptr, n_tx);   // t1 (in-place A)

    // ---- conv2: gather from t1=A, w1=B, then both epilogues ----
    gather_mean_kernel<<<grid_g_w, blk, 0, stream>>>(A, rp_w, deg_w, col_tw, mean_w, n_w);
    gather_mean_kernel<<<grid_g_tx, blk, 0, stream>>>(B, rp_tx, deg_tx, col_wt, mean_tx, n_tx);
    sage_mfma_kernel<false><<<grid_sage_w, blk, 0, stream>>>(
        mean_w, B, Wl2_tw, bl2_tw, Wr2_tw,
        out_w2, nullptr, nullptr, nullptr, nullptr, nullptr, nullptr, n_w);   // w2 -> f32 out
    sage_mfma_kernel<true><<<grid_sage_tx, blk, 0, stream>>>(
        mean_tx, A, Wl2_wt, bl2_wt, Wr2_wt,
        out_t2, nullptr, Wh1, bh1, Wh2, bh2, out_logits, n_tx);               // t2 + logits
}

// Round 10
// 1606.673 us; speedup vs baseline: 1.0992x; 1.0202x over previous
//
#include <hip/hip_runtime.h>
#include <hip/hip_bf16.h>

typedef __hip_bfloat16 bf16;
typedef __attribute__((ext_vector_type(8))) short bf16x8;   // 8 bf16 = 4 VGPR
typedef __attribute__((ext_vector_type(4))) float f32x4;    // MFMA accumulator

__device__ __forceinline__ float b2f(bf16 v) { return __bfloat162float(v); }
__device__ __forceinline__ bf16 f2b(float v) { return __float2bfloat16(v); }
__device__ __forceinline__ unsigned short f2bb(float v) {   // RNE f32->bf16 bits
    unsigned int u = __float_as_uint(v);
    u += 0x7fffu + ((u >> 16) & 1u);
    return (unsigned short)(u >> 16);
}
// bf16x8 element k (compile-time k) -> f32 via bit shift
__device__ __forceinline__ float b2fx(bf16x8 v, int k) {
    return __uint_as_float(((unsigned int)(unsigned short)v[k]) << 16);
}

__device__ __forceinline__ f32x4 mfma16(bf16x8 a, bf16x8 b, f32x4 c) {
    return __builtin_amdgcn_mfma_f32_16x16x32_bf16(a, b, c, 0, 0, 0);
}

// Gather a B-fragment: rows k0..k0+7 of column col from row-major W[64][64] f32.
__device__ __forceinline__ bf16x8 load_bfrag(const float* __restrict__ W, int k0, int col) {
    bf16x8 f;
#pragma unroll
    for (int j = 0; j < 8; ++j)
        f[j] = (short)f2bb(W[(size_t)(k0 + j) * 64 + col]);
    return f;
}

// Swizzled byte offset for the HEAD restage tile ([64][64 bf16], 128B rows).
__device__ __forceinline__ int swzH(int row, int b) {
    return row * 128 + (b ^ ((row & 7) << 4));
}

// ======================= CSR build (merged: both relations per launch) =======
__global__ void count2_kernel(const int* __restrict__ dst_tw, int* __restrict__ deg_w, int ne_tw,
                              const int* __restrict__ dst_wt, int* __restrict__ deg_tx, int ne_wt) {
    int e = blockIdx.x * 256 + threadIdx.x;
    if (e < ne_tw) atomicAdd(&deg_w[dst_tw[e]], 1);
    else {
        int e2 = e - ne_tw;
        if (e2 < ne_wt) atomicAdd(&deg_tx[dst_wt[e2]], 1);
    }
}

// block-local exclusive scan over 1024 elems (256 thr x 4); writes block totals
__global__ void scan1m_kernel(const int* __restrict__ dw, int* __restrict__ ew,
                              int* __restrict__ pw, int nw, int npw,
                              const int* __restrict__ dt, int* __restrict__ et,
                              int* __restrict__ pt, int nt) {
    __shared__ int sT[256];
    const int* deg; int* excl; int* partial; int n; int b;
    if ((int)blockIdx.x < npw) { deg = dw; excl = ew; partial = pw; n = nw; b = blockIdx.x; }
    else { deg = dt; excl = et; partial = pt; n = nt; b = blockIdx.x - npw; }
    int tid = threadIdx.x;
    int base = b * 1024 + tid * 4;
    int v0 = (base + 0 < n) ? deg[base + 0] : 0;
    int v1 = (base + 1 < n) ? deg[base + 1] : 0;
    int v2 = (base + 2 < n) ? deg[base + 2] : 0;
    int v3 = (base + 3 < n) ? deg[base + 3] : 0;
    int t = v0 + v1 + v2 + v3;
    sT[tid] = t;
    __syncthreads();
    for (int off = 1; off < 256; off <<= 1) {   // Hillis-Steele inclusive
        int x = (tid >= off) ? sT[tid - off] : 0;
        __syncthreads();
        sT[tid] += x;
        __syncthreads();
    }
    int et2 = sT[tid] - t;
    if (tid == 255) partial[b] = sT[255];
    if (base + 0 < n) excl[base + 0] = et2;
    if (base + 1 < n) excl[base + 1] = et2 + v0;
    if (base + 2 < n) excl[base + 2] = et2 + v0 + v1;
    if (base + 3 < n) excl[base + 3] = et2 + v0 + v1 + v2;
}

// block 0 scans part_w, block 1 scans part_tx (each single-block full scan)
__global__ void scan2m_kernel(int* __restrict__ pw, int npw, int* __restrict__ pt, int npt) {
    __shared__ int sT[256];
    __shared__ int carry;
    int* partial = blockIdx.x ? pt : pw;
    int np = blockIdx.x ? npt : npw;
    int tid = threadIdx.x;
    if (tid == 0) carry = 0;
    __syncthreads();
    for (int c = 0; c < np; c += 256) {
        int i = c + tid;
        int v = (i < np) ? partial[i] : 0;
        sT[tid] = v;
        __syncthreads();
        for (int off = 1; off < 256; off <<= 1) {
            int x = (tid >= off) ? sT[tid - off] : 0;
            __syncthreads();
            sT[tid] += x;
            __syncthreads();
        }
        int incl = sT[tid];
        int total = sT[255];
        if (i < np) partial[i] = carry + incl - v;
        __syncthreads();
        if (tid == 0) carry += total;
        __syncthreads();
    }
}

// rowptr[i] = cursor[i] = excl[i] + partial[i>>10]  (cursor may alias excl)
__global__ void scan3m_kernel(const int* __restrict__ ew, const int* __restrict__ pw,
                              int* __restrict__ rw, int* __restrict__ cw, int nw, int nbw,
                              const int* __restrict__ et, const int* __restrict__ pt,
                              int* __restrict__ rt, int* __restrict__ ct, int nt) {
    int b = blockIdx.x;
    const int* excl; const int* partial; int* rp; int* cur; int n; int i;
    if (b < nbw) { i = b * 256 + threadIdx.x; excl = ew; partial = pw; rp = rw; cur = cw; n = nw; }
    else { i = (b - nbw) * 256 + threadIdx.x; excl = et; partial = pt; rp = rt; cur = ct; n = nt; }
    if (i < n) {
        int v = excl[i] + partial[i >> 10];
        rp[i] = v;
        cur[i] = v;
    }
}

__global__ void scatter2_kernel(const int* __restrict__ src_tw, const int* __restrict__ dst_tw,
                                int* __restrict__ cur_w, int* __restrict__ col_tw, int ne_tw,
                                const int* __restrict__ src_wt, const int* __restrict__ dst_wt,
                                int* __restrict__ cur_tx, int* __restrict__ col_wt, int ne_wt) {
    int e = blockIdx.x * 256 + threadIdx.x;
    if (e < ne_tw) {
        int p = atomicAdd(&cur_w[dst_tw[e]], 1);
        col_tw[p] = src_tw[e];
    } else {
        int e2 = e - ne_tw;
        if (e2 < ne_wt) {
            int p = atomicAdd(&cur_tx[dst_wt[e2]], 1);
            col_wt[p] = src_wt[e2];
        }
    }
}

// ======================= gather mean (round-7 proven body) ===================
// mean[i,:] = (1/max(deg_i,1)) * sum_{e in row i} h[col[e], :]   (bf16 out)
// 8 rows/wave, 8 lanes/row, 8 features/lane; 16B bf16x8 loads; chunk-of-8
// clamped indices + {0,1} weights (bit-identical summation order).
#define GM_ACC(x, w) \
    a0 += (w) * b2fx(x, 0); a1 += (w) * b2fx(x, 1); \
    a2 += (w) * b2fx(x, 2); a3 += (w) * b2fx(x, 3); \
    a4 += (w) * b2fx(x, 4); a5 += (w) * b2fx(x, 5); \
    a6 += (w) * b2fx(x, 6); a7 += (w) * b2fx(x, 7);

__device__ __forceinline__ void gather_body(const bf16* __restrict__ h,
                                            const int* __restrict__ rowptr,
                                            const int* __restrict__ deg,
                                            const int* __restrict__ col,
                                            bf16* __restrict__ mean, int n, int bid) {
    int tid = threadIdx.x;
    int row = bid * 32 + (tid >> 3);          // 32 rows per block, 8 lanes each
    if (row >= n) return;
    int fg = tid & 7;                         // feature octet: cols fg*8..fg*8+7
    int base = rowptr[row];
    int d = deg[row];
    int lasto = (d > 0) ? d - 1 : 0;
    float a0 = 0.f, a1 = 0.f, a2 = 0.f, a3 = 0.f;
    float a4 = 0.f, a5 = 0.f, a6 = 0.f, a7 = 0.f;
    for (int e0 = 0; e0 < d; e0 += 8) {
        int o1 = (e0 + 1 < d) ? e0 + 1 : lasto;
        int o2 = (e0 + 2 < d) ? e0 + 2 : lasto;
        int o3 = (e0 + 3 < d) ? e0 + 3 : lasto;
        int o4 = (e0 + 4 < d) ? e0 + 4 : lasto;
        int o5 = (e0 + 5 < d) ? e0 + 5 : lasto;
        int o6 = (e0 + 6 < d) ? e0 + 6 : lasto;
        int o7 = (e0 + 7 < d) ? e0 + 7 : lasto;
        int s0 = col[base + e0], s1 = col[base + o1];
        int s2 = col[base + o2], s3 = col[base + o3];
        int s4 = col[base + o4], s5 = col[base + o5];
        int s6 = col[base + o6], s7 = col[base + o7];
        bf16x8 x0 = *(const bf16x8*)(h + ((size_t)s0 << 6) + (fg << 3));
        bf16x8 x1 = *(const bf16x8*)(h + ((size_t)s1 << 6) + (fg << 3));
        bf16x8 x2 = *(const bf16x8*)(h + ((size_t)s2 << 6) + (fg << 3));
        bf16x8 x3 = *(const bf16x8*)(h + ((size_t)s3 << 6) + (fg << 3));
        bf16x8 x4 = *(const bf16x8*)(h + ((size_t)s4 << 6) + (fg << 3));
        bf16x8 x5 = *(const bf16x8*)(h + ((size_t)s5 << 6) + (fg << 3));
        bf16x8 x6 = *(const bf16x8*)(h + ((size_t)s6 << 6) + (fg << 3));
        bf16x8 x7 = *(const bf16x8*)(h + ((size_t)s7 << 6) + (fg << 3));
        float w1 = (e0 + 1 < d) ? 1.f : 0.f;
        float w2 = (e0 + 2 < d) ? 1.f : 0.f;
        float w3 = (e0 + 3 < d) ? 1.f : 0.f;
        float w4 = (e0 + 4 < d) ? 1.f : 0.f;
        float w5 = (e0 + 5 < d) ? 1.f : 0.f;
        float w6 = (e0 + 6 < d) ? 1.f : 0.f;
        float w7 = (e0 + 7 < d) ? 1.f : 0.f;
        GM_ACC(x0, 1.f)
        GM_ACC(x1, w1)
        GM_ACC(x2, w2)
        GM_ACC(x3, w3)
        GM_ACC(x4, w4)
        GM_ACC(x5, w5)
        GM_ACC(x6, w6)
        GM_ACC(x7, w7)
    }
    float dd = fmaxf((float)d, 1.f);
    bf16x8 o;
    o[0] = (short)f2bb(a0 / dd); o[1] = (short)f2bb(a1 / dd);
    o[2] = (short)f2bb(a2 / dd); o[3] = (short)f2bb(a3 / dd);
    o[4] = (short)f2bb(a4 / dd); o[5] = (short)f2bb(a5 / dd);
    o[6] = (short)f2bb(a6 / dd); o[7] = (short)f2bb(a7 / dd);
    *(bf16x8*)(mean + ((size_t)row << 6) + (fg << 3)) = o;
}

// Merged: blocks [0,gbw) gather wallets, rest gather tx (independent jobs,
// one launch -> w work overlaps under the long tx tail).
__global__ __launch_bounds__(256)
void gather2_kernel(const bf16* __restrict__ hw, const int* __restrict__ rpw,
                    const int* __restrict__ dw, const int* __restrict__ cw,
                    bf16* __restrict__ mw, int nw, int gbw,
                    const bf16* __restrict__ ht, const int* __restrict__ rpt,
                    const int* __restrict__ dt, const int* __restrict__ ct,
                    bf16* __restrict__ mt, int nt) {
    if ((int)blockIdx.x < gbw) gather_body(hw, rpw, dw, cw, mw, nw, blockIdx.x);
    else                       gather_body(ht, rpt, dt, ct, mt, nt, blockIdx.x - gbw);
}

// ======================= SAGE epilogue body (MFMA, LDS-free, pipelined) ======
// out[i,j] = relu( mean[i,:] . Wl[:,j] + bl[j] + xd[i,:] . Wr[:,j] )
// Per-wave streaming: wave owns 16 rows of each 64-row group, A-fragments read
// directly from global. SOFTWARE PIPELINE: group g+1's 4 fragments are
// prefetched before group g's MFMA+stores (disjoint rows -> in-place safe;
// hides the ~500cy global-load latency at low occupancy). No barriers.
// HEAD: t2 restaged bf16 into sH (wave-local rows, per-wave LDS program
// order), K=64 MFMA GEMM + 16-lane shfl_xor reduce for the 64->2 contraction.
template<bool HEAD>
__device__ __forceinline__ void sage_body(
        const bf16* __restrict__ mean, const bf16* __restrict__ xd,
        const float* __restrict__ Wl, const float* __restrict__ bl,
        const float* __restrict__ Wr,
        float* __restrict__ outf, bf16* __restrict__ outb,
        const float* __restrict__ Wh1, const float* __restrict__ bh1,
        const float* __restrict__ Wh2, const float* __restrict__ bh2,
        float* __restrict__ logits, int n, int bid, short* sH) {
    int tid = threadIdx.x;
    int lane = tid & 63, w = tid >> 6;
    int lm = lane & 15, lq = lane >> 4;

    // --- weight fragments: once per block, held in registers ---
    bf16x8 wc[4][4];   // [col-tile][k-step]; ks 0,1 = Wl(k0=0,32), ks 2,3 = Wr
    bf16x8 wh[4][2];
    float blv[4], h1v[4], w2a[4], w2b[4];
#pragma unroll
    for (int ct = 0; ct < 4; ++ct) {
        int colc = ct * 16 + lm;
        wc[ct][0] = load_bfrag(Wl, lq * 8, colc);
        wc[ct][1] = load_bfrag(Wl, 32 + lq * 8, colc);
        wc[ct][2] = load_bfrag(Wr, lq * 8, colc);
        wc[ct][3] = load_bfrag(Wr, 32 + lq * 8, colc);
        blv[ct] = bl[colc];
        if (HEAD) {
            wh[ct][0] = load_bfrag(Wh1, lq * 8, colc);
            wh[ct][1] = load_bfrag(Wh1, 32 + lq * 8, colc);
            h1v[ct] = bh1[colc];
            w2a[ct] = Wh2[colc * 2 + 0];
            w2b[ct] = Wh2[colc * 2 + 1];
        }
    }
    float b20 = 0.f, b21 = 0.f;
    if (HEAD) { b20 = bh2[0]; b21 = bh2[1]; }

    int larow = w * 16 + lm;             // local A-fragment row (0..63)
    int row0 = bid * 512;
    if (row0 >= n) return;
    // preload group 0 fragments
    int ar = row0 + larow; ar = (ar < n) ? ar : (n - 1);
    const bf16* mrow = mean + ((size_t)ar << 6);
    const bf16* xrow = xd + ((size_t)ar << 6);
    bf16x8 a0 = *(const bf16x8*)(mrow + lq * 8);        // mean k 0..31
    bf16x8 a1 = *(const bf16x8*)(mrow + 32 + lq * 8);   // mean k 32..63
    bf16x8 a2 = *(const bf16x8*)(xrow + lq * 8);        // xd   k 0..31
    bf16x8 a3 = *(const bf16x8*)(xrow + 32 + lq * 8);   // xd   k 32..63

    for (int g = 0; g < 8; ++g) {
        int gr0 = row0 + g * 64;
        if (gr0 >= n) break;
        // prefetch next group's fragments (rows gr0+64.. — disjoint from the
        // rows written below, so in-place outb==xd stays safe)
        bf16x8 n0 = a0, n1 = a1, n2 = a2, n3 = a3;
        if (g < 7) {
            int nr = gr0 + 64 + larow; nr = (nr < n) ? nr : (n - 1);
            const bf16* nm = mean + ((size_t)nr << 6);
            const bf16* nx = xd + ((size_t)nr << 6);
            n0 = *(const bf16x8*)(nm + lq * 8);
            n1 = *(const bf16x8*)(nm + 32 + lq * 8);
            n2 = *(const bf16x8*)(nx + lq * 8);
            n3 = *(const bf16x8*)(nx + 32 + lq * 8);
        }
#pragma unroll
        for (int ct = 0; ct < 4; ++ct) {
            f32x4 acc = {0.f, 0.f, 0.f, 0.f};
            acc = mfma16(a0, wc[ct][0], acc);
            acc = mfma16(a1, wc[ct][1], acc);
            acc = mfma16(a2, wc[ct][2], acc);
            acc = mfma16(a3, wc[ct][3], acc);
            int colc = ct * 16 + lm;
#pragma unroll
            for (int r = 0; r < 4; ++r) {
                int lrow = w * 16 + lq * 4 + r;
                int grow = gr0 + lrow;
                float v = fmaxf(acc[r] + blv[ct], 0.f);
                if (grow < n) {
                    if (outf) outf[(size_t)grow * 64 + colc] = v;
                    if (outb) outb[(size_t)grow * 64 + colc] = f2b(v);
                }
                if (HEAD)   // wave-local restage; same wave reads below
                    *(short*)((char*)sH + swzH(lrow, colc * 2)) = (short)f2bb(v);
            }
        }
        if (HEAD) {
            bf16x8 h0 = *(const bf16x8*)((char*)sH + swzH(larow, lq * 16));
            bf16x8 h1 = *(const bf16x8*)((char*)sH + swzH(larow, 64 + lq * 16));
            float qa0 = 0.f, qa1 = 0.f, qa2 = 0.f, qa3 = 0.f;
            float qb0 = 0.f, qb1 = 0.f, qb2 = 0.f, qb3 = 0.f;
#pragma unroll
            for (int ct = 0; ct < 4; ++ct) {
                f32x4 acc = {0.f, 0.f, 0.f, 0.f};
                acc = mfma16(h0, wh[ct][0], acc);
                acc = mfma16(h1, wh[ct][1], acc);
                float hb = h1v[ct];
                float h_0 = fmaxf(acc[0] + hb, 0.f);
                float h_1 = fmaxf(acc[1] + hb, 0.f);
                float h_2 = fmaxf(acc[2] + hb, 0.f);
                float h_3 = fmaxf(acc[3] + hb, 0.f);
                qa0 += h_0 * w2a[ct]; qb0 += h_0 * w2b[ct];
                qa1 += h_1 * w2a[ct]; qb1 += h_1 * w2b[ct];
                qa2 += h_2 * w2a[ct]; qb2 += h_2 * w2b[ct];
                qa3 += h_3 * w2a[ct]; qb3 += h_3 * w2b[ct];
            }
#pragma unroll
            for (int m = 8; m; m >>= 1) {   // reduce over the 16-lane quad
                qa0 += __shfl_xor(qa0, m); qb0 += __shfl_xor(qb0, m);
                qa1 += __shfl_xor(qa1, m); qb1 += __shfl_xor(qb1, m);
                qa2 += __shfl_xor(qa2, m); qb2 += __shfl_xor(qb2, m);
                qa3 += __shfl_xor(qa3, m); qb3 += __shfl_xor(qb3, m);
            }
            int rowb = gr0 + w * 16 + lq * 4;
            if (lm == 0) {
                if (rowb + 0 < n) { logits[(size_t)(rowb + 0) * 2 + 0] = qa0 + b20;
                                    logits[(size_t)(rowb + 0) * 2 + 1] = qb0 + b21; }
                if (rowb + 1 < n) { logits[(size_t)(rowb + 1) * 2 + 0] = qa1 + b20;
                                    logits[(size_t)(rowb + 1) * 2 + 1] = qb1 + b21; }
                if (rowb + 2 < n) { logits[(size_t)(rowb + 2) * 2 + 0] = qa2 + b20;
                                    logits[(size_t)(rowb + 2) * 2 + 1] = qb2 + b21; }
                if (rowb + 3 < n) { logits[(size_t)(rowb + 3) * 2 + 0] = qa3 + b20;
                                    logits[(size_t)(rowb + 3) * 2 + 1] = qb3 + b21; }
            }
        }
        a0 = n0; a1 = n1; a2 = n2; a3 = n3;
    }
}

// Merged: blocks [0,gbw) run the wallet job (never HEAD), rest run the tx job
// (HEAD per template). Jobs are independent (disjoint buffers).
template<bool HEAD>
__global__ __launch_bounds__(256, 2)
void sage2_kernel(const bf16* __restrict__ mw, const bf16* __restrict__ xw,
                  const float* __restrict__ Wlw, const float* __restrict__ blw,
                  const float* __restrict__ Wrw,
                  float* __restrict__ outfw, bf16* __restrict__ outbw, int nw, int gbw,
                  const bf16* __restrict__ mt, const bf16* __restrict__ xt,
                  const float* __restrict__ Wlt, const float* __restrict__ blt,
                  const float* __restrict__ Wrt,
                  float* __restrict__ outft, bf16* __restrict__ outbt,
                  const float* __restrict__ Wh1, const float* __restrict__ bh1,
                  const float* __restrict__ Wh2, const float* __restrict__ bh2,
                  float* __restrict__ logits, int nt) {
    __shared__ __align__(16) short sH[HEAD ? 64 * 64 : 8];
    if ((int)blockIdx.x < gbw)
        sage_body<false>(mw, xw, Wlw, blw, Wrw, outfw, outbw,
                         nullptr, nullptr, nullptr, nullptr, nullptr, nw, blockIdx.x, sH);
    else
        sage_body<HEAD>(mt, xt, Wlt, blt, Wrt, outft, outbt,
                        Wh1, bh1, Wh2, bh2, logits, nt, blockIdx.x - gbw, sH);
}

// ======================= input projection, F=64 (MFMA, pipelined) ============
// out[i,j] = x[i,:] . W[:,j] + b[j]  (no relu). LDS-free per-wave streaming
// with next-group prefetch (x is read-only, trivially safe).
__global__ __launch_bounds__(256)
void proj64_mfma_kernel(const float* __restrict__ x, const float* __restrict__ W,
                        const float* __restrict__ b, bf16* __restrict__ out, int n) {
    int tid = threadIdx.x;
    int lane = tid & 63, w = tid >> 6;
    int lm = lane & 15, lq = lane >> 4;

    bf16x8 wc[4][2];
    float bv[4];
#pragma unroll
    for (int ct = 0; ct < 4; ++ct) {
        int colc = ct * 16 + lm;
        wc[ct][0] = load_bfrag(W, lq * 8, colc);
        wc[ct][1] = load_bfrag(W, 32 + lq * 8, colc);
        bv[ct] = b[colc];
    }

    int larow = w * 16 + lm;
    int row0 = blockIdx.x * 512;
    if (row0 >= n) return;
    int ar = row0 + larow; ar = (ar < n) ? ar : (n - 1);
    const float* xrow = x + ((size_t)ar << 6);
    float4 p0 = *(const float4*)(xrow + lq * 8);
    float4 p1 = *(const float4*)(xrow + lq * 8 + 4);
    float4 p2 = *(const float4*)(xrow + 32 + lq * 8);
    float4 p3 = *(const float4*)(xrow + 32 + lq * 8 + 4);

    for (int g = 0; g < 8; ++g) {
        int gr0 = row0 + g * 64;
        if (gr0 >= n) break;
        float4 q0 = p0, q1 = p1, q2 = p2, q3 = p3;
        if (g < 7) {   // prefetch next group
            int nr = gr0 + 64 + larow; nr = (nr < n) ? nr : (n - 1);
            const float* nx = x + ((size_t)nr << 6);
            q0 = *(const float4*)(nx + lq * 8);
            q1 = *(const float4*)(nx + lq * 8 + 4);
            q2 = *(const float4*)(nx + 32 + lq * 8);
            q3 = *(const float4*)(nx + 32 + lq * 8 + 4);
        }
        bf16x8 a0, a1;
        a0[0] = (short)f2bb(p0.x); a0[1] = (short)f2bb(p0.y);
        a0[2] = (short)f2bb(p0.z); a0[3] = (short)f2bb(p0.w);
        a0[4] = (short)f2bb(p1.x); a0[5] = (short)f2bb(p1.y);
        a0[6] = (short)f2bb(p1.z); a0[7] = (short)f2bb(p1.w);
        a1[0] = (short)f2bb(p2.x); a1[1] = (short)f2bb(p2.y);
        a1[2] = (short)f2bb(p2.z); a1[3] = (short)f2bb(p2.w);
        a1[4] = (short)f2bb(p3.x); a1[5] = (short)f2bb(p3.y);
        a1[6] = (short)f2bb(p3.z); a1[7] = (short)f2bb(p3.w);
#pragma unroll
        for (int ct = 0; ct < 4; ++ct) {
            f32x4 acc = {0.f, 0.f, 0.f, 0.f};
            acc = mfma16(a0, wc[ct][0], acc);
            acc = mfma16(a1, wc[ct][1], acc);
            int colc = ct * 16 + lm;
#pragma unroll
            for (int r = 0; r < 4; ++r) {
                int grow = gr0 + w * 16 + lq * 4 + r;
                if (grow < n)
                    out[(size_t)grow * 64 + colc] = f2b(acc[r] + bv[ct]);
            }
        }
        p0 = q0; p1 = q1; p2 = q2; p3 = q3;
    }
}

// out[i,j] = sum_k x[i,k]*W[k,j] + b[j]   (x,W,b f32 -> out bf16), no relu
// (VALU version, used only for the small F=32 projection)
template<int F>
__global__ void proj_kernel(const float* __restrict__ x, const float* __restrict__ W,
                            const float* __restrict__ b, bf16* __restrict__ out, int n) {
    __shared__ float sW[F][64];
    __shared__ float sb[64];
    __shared__ float sx[16][F];
    int tid = threadIdx.x;
    for (int idx = tid; idx < F * 16; idx += 256)
        ((float4*)sW)[idx] = ((const float4*)W)[idx];
    if (tid < 64) sb[tid] = b[tid];
    int base = blockIdx.x * 64;
    int w = tid >> 6, j = tid & 63;
    int lw = w * 4;
    for (int g = 0; g < 4; ++g) {
        int row0 = base + g * 16;
        __syncthreads();
        for (int idx = tid; idx < 4 * F; idx += 256) {
            int rr = idx / (F / 4), c4 = idx - rr * (F / 4);
            int row = row0 + rr;
            float4 v = (row < n) ? ((const float4*)x)[(size_t)row * (F / 4) + c4]
                                 : make_float4(0.f, 0.f, 0.f, 0.f);
            *(float4*)&sx[rr][c4 * 4] = v;
        }
        __syncthreads();
        float a0 = sb[j], a1 = sb[j], a2 = sb[j], a3 = sb[j];
#pragma unroll 2
        for (int k = 0; k < F; k += 4) {
            float w0 = sW[k][j], w1 = sW[k + 1][j], w2 = sW[k + 2][j], w3 = sW[k + 3][j];
            float4 m0 = *(const float4*)&sx[lw + 0][k];
            float4 m1 = *(const float4*)&sx[lw + 1][k];
            float4 m2 = *(const float4*)&sx[lw + 2][k];
            float4 m3 = *(const float4*)&sx[lw + 3][k];
            a0 += m0.x * w0 + m0.y * w1 + m0.z * w2 + m0.w * w3;
            a1 += m1.x * w0 + m1.y * w1 + m1.z * w2 + m1.w * w3;
            a2 += m2.x * w0 + m2.y * w1 + m2.z * w2 + m2.w * w3;
            a3 += m3.x * w0 + m3.y * w1 + m3.z * w2 + m3.w * w3;
        }
        int r0 = row0 + lw;
        if (r0 + 0 < n) out[(size_t)(r0 + 0) * 64 + j] = f2b(a0);
        if (r0 + 1 < n) out[(size_t)(r0 + 1) * 64 + j] = f2b(a1);
        if (r0 + 2 < n) out[(size_t)(r0 + 2) * 64 + j] = f2b(a2);
        if (r0 + 3 < n) out[(size_t)(r0 + 3) * 64 + j] = f2b(a3);
    }
}

extern "C" void kernel_launch(void* const* d_in, const int* in_sizes, int n_in,
                              void* d_out, int out_size, void* d_ws, size_t ws_size,
                              hipStream_t stream) {
    const float* x_tx   = (const float*)d_in[0];
    const float* x_w    = (const float*)d_in[1];
    const int*   src_tw = (const int*)d_in[2];
    const int*   dst_tw = (const int*)d_in[3];
    const int*   src_wt = (const int*)d_in[4];
    const int*   dst_wt = (const int*)d_in[5];
    const float* Win_tx = (const float*)d_in[6];
    const float* bin_tx = (const float*)d_in[7];
    const float* Win_w  = (const float*)d_in[8];
    const float* bin_w  = (const float*)d_in[9];
    const float* Wl1_tw = (const float*)d_in[10];
    const float* bl1_tw = (const float*)d_in[11];
    const float* Wr1_tw = (const float*)d_in[12];
    const float* Wl1_wt = (const float*)d_in[13];
    const float* bl1_wt = (const float*)d_in[14];
    const float* Wr1_wt = (const float*)d_in[15];
    const float* Wl2_tw = (const float*)d_in[16];
    const float* bl2_tw = (const float*)d_in[17];
    const float* Wr2_tw = (const float*)d_in[18];
    const float* Wl2_wt = (const float*)d_in[19];
    const float* bl2_wt = (const float*)d_in[20];
    const float* Wr2_wt = (const float*)d_in[21];
    const float* Wh1    = (const float*)d_in[22];
    const float* bh1    = (const float*)d_in[23];
    const float* Wh2    = (const float*)d_in[24];
    const float* bh2    = (const float*)d_in[25];

    const int n_tx  = in_sizes[0] / 64;
    const int n_w   = in_sizes[1] / 32;
    const int ne_tw = in_sizes[2];
    const int ne_wt = in_sizes[4];

    // ---- workspace layout (~351 MB) ----
    bf16* mean_tx = (bf16*)d_ws;                          // n_tx*64 bf16 (128 MB)
    bf16* mean_w  = mean_tx + (size_t)n_tx * 64;          // n_w *64 bf16 ( 32 MB)
    bf16* A       = mean_w + (size_t)n_w * 64;            // n_tx*64 bf16: h_tx->t1 (in-place)
    bf16* B       = A + (size_t)n_tx * 64;                // n_w *64 bf16: h_w ->w1 (in-place)
    int*  deg_w   = (int*)(B + (size_t)n_w * 64);         // n_w
    int*  deg_tx  = deg_w + n_w;                          // n_tx
    int*  rp_w    = deg_tx + n_tx;                        // n_w
    int*  rp_tx   = rp_w + n_w;                           // n_tx
    int*  cur_w   = rp_tx + n_tx;                         // n_w  (excl scratch, then cursor)
    int*  cur_tx  = cur_w + n_w;                          // n_tx
    int*  col_tw  = cur_tx + n_tx;                        // ne_tw
    int*  col_wt  = col_tw + ne_tw;                       // ne_wt
    int*  part_w  = col_wt + ne_wt;                       // <=4096
    int*  part_tx = part_w + 4096;                        // <=4096

    float* out_logits = (float*)d_out;
    float* out_t2 = out_logits + (size_t)n_tx * 2;
    float* out_w2 = out_t2 + (size_t)n_tx * 64;

    dim3 blk(256);
    int grid_proj_tx = (n_tx + 511) / 512;
    int grid_proj_w  = (n_w + 63) / 64;
    int gs_w  = (n_w + 511) / 512;
    int gs_tx = (n_tx + 511) / 512;
    int gg_w  = (n_w + 31) / 32;
    int gg_tx = (n_tx + 31) / 32;
    int grid_e = (ne_tw + ne_wt + 255) / 256;
    int np_w  = (n_w + 1023) / 1024;
    int np_tx = (n_tx + 1023) / 1024;
    int nbw = (n_w + 255) / 256;
    int nbt = (n_tx + 255) / 256;

    // ---- CSR build (merged launches; graph static, reused by both convs) ----
    hipMemsetAsync(deg_w, 0, (size_t)n_w * sizeof(int), stream);
    hipMemsetAsync(deg_tx, 0, (size_t)n_tx * sizeof(int), stream);
    count2_kernel<<<grid_e, blk, 0, stream>>>(dst_tw, deg_w, ne_tw, dst_wt, deg_tx, ne_wt);
    scan1m_kernel<<<np_w + np_tx, blk, 0, stream>>>(deg_w, cur_w, part_w, n_w, np_w,
                                                    deg_tx, cur_tx, part_tx, n_tx);
    scan2m_kernel<<<2, blk, 0, stream>>>(part_w, np_w, part_tx, np_tx);
    scan3m_kernel<<<nbw + nbt, blk, 0, stream>>>(cur_w, part_w, rp_w, cur_w, n_w, nbw,
                                                 cur_tx, part_tx, rp_tx, cur_tx, n_tx);
    scatter2_kernel<<<grid_e, blk, 0, stream>>>(src_tw, dst_tw, cur_w, col_tw, ne_tw,
                                                src_wt, dst_wt, cur_tx, col_wt, ne_wt);

    // ---- input projections ----
    proj64_mfma_kernel<<<grid_proj_tx, blk, 0, stream>>>(x_tx, Win_tx, bin_tx, A, n_tx);
    proj_kernel<32><<<grid_proj_w, blk, 0, stream>>>(x_w, Win_w, bin_w, B, n_w);

    // ---- conv1: merged gathers, then merged sages (both in-place) ----
    gather2_kernel<<<gg_w + gg_tx, blk, 0, stream>>>(
        A, rp_w, deg_w, col_tw, mean_w, n_w, gg_w,
        B, rp_tx, deg_tx, col_wt, mean_tx, n_tx);
    sage2_kernel<false><<<gs_w + gs_tx, blk, 0, stream>>>(
        mean_w, B, Wl1_tw, bl1_tw, Wr1_tw, nullptr, B, n_w, gs_w,
        mean_tx, A, Wl1_wt, bl1_wt, Wr1_wt, nullptr, A,
        nullptr, nullptr, nullptr, nullptr, nullptr, n_tx);

    // ---- conv2: merged gathers, then merged sages (f32 outputs; tx has HEAD) ----
    gather2_kernel<<<gg_w + gg_tx, blk, 0, stream>>>(
        A, rp_w, deg_w, col_tw, mean_w, n_w, gg_w,
        B, rp_tx, deg_tx, col_wt, mean_tx, n_tx);
    sage2_kernel<true><<<gs_w + gs_tx, blk, 0, stream>>>(
        mean_w, B, Wl2_tw, bl2_tw, Wr2_tw, out_w2, nullptr, n_w, gs_w,
        mean_tx, A, Wl2_wt, bl2_wt, Wr2_wt, out_t2, nullptr,
        Wh1, bh1, Wh2, bh2, out_logits, n_tx);
}

// Round 11
// 1369.565 us; speedup vs baseline: 1.2895x; 1.1731x over previous
//
#include <hip/hip_runtime.h>
#include <hip/hip_bf16.h>

typedef __hip_bfloat16 bf16;
typedef __attribute__((ext_vector_type(8))) short bf16x8;   // 8 bf16 = 4 VGPR
typedef __attribute__((ext_vector_type(4))) float f32x4;    // MFMA accumulator

__device__ __forceinline__ float b2f(bf16 v) { return __bfloat162float(v); }
__device__ __forceinline__ bf16 f2b(float v) { return __float2bfloat16(v); }
__device__ __forceinline__ unsigned short f2bb(float v) {   // RNE f32->bf16 bits
    unsigned int u = __float_as_uint(v);
    u += 0x7fffu + ((u >> 16) & 1u);
    return (unsigned short)(u >> 16);
}
// bf16x8 element k (compile-time k) -> f32 via bit shift
__device__ __forceinline__ float b2fx(bf16x8 v, int k) {
    return __uint_as_float(((unsigned int)(unsigned short)v[k]) << 16);
}

__device__ __forceinline__ f32x4 mfma16(bf16x8 a, bf16x8 b, f32x4 c) {
    return __builtin_amdgcn_mfma_f32_16x16x32_bf16(a, b, c, 0, 0, 0);
}

// Gather a B-fragment: rows k0..k0+7 of column col from row-major W[64][64] f32.
__device__ __forceinline__ bf16x8 load_bfrag(const float* __restrict__ W, int k0, int col) {
    bf16x8 f;
#pragma unroll
    for (int j = 0; j < 8; ++j)
        f[j] = (short)f2bb(W[(size_t)(k0 + j) * 64 + col]);
    return f;
}

// Swizzled byte offset for the HEAD restage tile ([64][64 bf16], 128B rows).
__device__ __forceinline__ int swzH(int row, int b) {
    return row * 128 + (b ^ ((row & 7) << 4));
}

// ======================= CSR build =======================
// Count AND capture each edge's within-row rank (ticket). rank writes are
// SEQUENTIAL (e-indexed) -> cheap; this removes the atomic from the scatter.
__global__ void count_rank2_kernel(const int* __restrict__ dst_tw, int* __restrict__ deg_w,
                                   int* __restrict__ rank_tw, int ne_tw,
                                   const int* __restrict__ dst_wt, int* __restrict__ deg_tx,
                                   int* __restrict__ rank_wt, int ne_wt) {
    int e = blockIdx.x * 256 + threadIdx.x;
    if (e < ne_tw) rank_tw[e] = atomicAdd(&deg_w[dst_tw[e]], 1);
    else {
        int e2 = e - ne_tw;
        if (e2 < ne_wt) rank_wt[e2] = atomicAdd(&deg_tx[dst_wt[e2]], 1);
    }
}

// block-local exclusive scan over 1024 elems (256 thr x 4); writes block totals
__global__ void scan1m_kernel(const int* __restrict__ dw, int* __restrict__ ew,
                              int* __restrict__ pw, int nw, int npw,
                              const int* __restrict__ dt, int* __restrict__ et,
                              int* __restrict__ pt, int nt) {
    __shared__ int sT[256];
    const int* deg; int* excl; int* partial; int n; int b;
    if ((int)blockIdx.x < npw) { deg = dw; excl = ew; partial = pw; n = nw; b = blockIdx.x; }
    else { deg = dt; excl = et; partial = pt; n = nt; b = blockIdx.x - npw; }
    int tid = threadIdx.x;
    int base = b * 1024 + tid * 4;
    int v0 = (base + 0 < n) ? deg[base + 0] : 0;
    int v1 = (base + 1 < n) ? deg[base + 1] : 0;
    int v2 = (base + 2 < n) ? deg[base + 2] : 0;
    int v3 = (base + 3 < n) ? deg[base + 3] : 0;
    int t = v0 + v1 + v2 + v3;
    sT[tid] = t;
    __syncthreads();
    for (int off = 1; off < 256; off <<= 1) {   // Hillis-Steele inclusive
        int x = (tid >= off) ? sT[tid - off] : 0;
        __syncthreads();
        sT[tid] += x;
        __syncthreads();
    }
    int et2 = sT[tid] - t;
    if (tid == 255) partial[b] = sT[255];
    if (base + 0 < n) excl[base + 0] = et2;
    if (base + 1 < n) excl[base + 1] = et2 + v0;
    if (base + 2 < n) excl[base + 2] = et2 + v0 + v1;
    if (base + 3 < n) excl[base + 3] = et2 + v0 + v1 + v2;
}

// block 0 scans part_w, block 1 scans part_tx (each single-block full scan)
__global__ void scan2m_kernel(int* __restrict__ pw, int npw, int* __restrict__ pt, int npt) {
    __shared__ int sT[256];
    __shared__ int carry;
    int* partial = blockIdx.x ? pt : pw;
    int np = blockIdx.x ? npt : npw;
    int tid = threadIdx.x;
    if (tid == 0) carry = 0;
    __syncthreads();
    for (int c = 0; c < np; c += 256) {
        int i = c + tid;
        int v = (i < np) ? partial[i] : 0;
        sT[tid] = v;
        __syncthreads();
        for (int off = 1; off < 256; off <<= 1) {
            int x = (tid >= off) ? sT[tid - off] : 0;
            __syncthreads();
            sT[tid] += x;
            __syncthreads();
        }
        int incl = sT[tid];
        int total = sT[255];
        if (i < np) partial[i] = carry + incl - v;
        __syncthreads();
        if (tid == 0) carry += total;
        __syncthreads();
    }
}

// rowptr[i] = excl[i] + partial[i>>10]   (no cursor needed: scatter is rank-based)
__global__ void scan3m_kernel(const int* __restrict__ ew, const int* __restrict__ pw,
                              int* __restrict__ rw, int nw, int nbw,
                              const int* __restrict__ et, const int* __restrict__ pt,
                              int* __restrict__ rt, int nt) {
    int b = blockIdx.x;
    const int* excl; const int* partial; int* rp; int n; int i;
    if (b < nbw) { i = b * 256 + threadIdx.x; excl = ew; partial = pw; rp = rw; n = nw; }
    else { i = (b - nbw) * 256 + threadIdx.x; excl = et; partial = pt; rp = rt; n = nt; }
    if (i < n) rp[i] = excl[i] + partial[i >> 10];
}

// ======================= proj bodies (for the fused front) ===================
// F=64 MFMA body: LDS-free per-wave streaming with next-group prefetch.
__device__ __forceinline__ void proj64_body(const float* __restrict__ x,
                                            const float* __restrict__ W,
                                            const float* __restrict__ b,
                                            bf16* __restrict__ out, int n, int bid) {
    int tid = threadIdx.x;
    int lane = tid & 63, w = tid >> 6;
    int lm = lane & 15, lq = lane >> 4;

    bf16x8 wc[4][2];
    float bv[4];
#pragma unroll
    for (int ct = 0; ct < 4; ++ct) {
        int colc = ct * 16 + lm;
        wc[ct][0] = load_bfrag(W, lq * 8, colc);
        wc[ct][1] = load_bfrag(W, 32 + lq * 8, colc);
        bv[ct] = b[colc];
    }

    int larow = w * 16 + lm;
    int row0 = bid * 512;
    if (row0 >= n) return;
    int ar = row0 + larow; ar = (ar < n) ? ar : (n - 1);
    const float* xrow = x + ((size_t)ar << 6);
    float4 p0 = *(const float4*)(xrow + lq * 8);
    float4 p1 = *(const float4*)(xrow + lq * 8 + 4);
    float4 p2 = *(const float4*)(xrow + 32 + lq * 8);
    float4 p3 = *(const float4*)(xrow + 32 + lq * 8 + 4);

    for (int g = 0; g < 8; ++g) {
        int gr0 = row0 + g * 64;
        if (gr0 >= n) break;
        float4 q0 = p0, q1 = p1, q2 = p2, q3 = p3;
        if (g < 7) {   // prefetch next group
            int nr = gr0 + 64 + larow; nr = (nr < n) ? nr : (n - 1);
            const float* nx = x + ((size_t)nr << 6);
            q0 = *(const float4*)(nx + lq * 8);
            q1 = *(const float4*)(nx + lq * 8 + 4);
            q2 = *(const float4*)(nx + 32 + lq * 8);
            q3 = *(const float4*)(nx + 32 + lq * 8 + 4);
        }
        bf16x8 a0, a1;
        a0[0] = (short)f2bb(p0.x); a0[1] = (short)f2bb(p0.y);
        a0[2] = (short)f2bb(p0.z); a0[3] = (short)f2bb(p0.w);
        a0[4] = (short)f2bb(p1.x); a0[5] = (short)f2bb(p1.y);
        a0[6] = (short)f2bb(p1.z); a0[7] = (short)f2bb(p1.w);
        a1[0] = (short)f2bb(p2.x); a1[1] = (short)f2bb(p2.y);
        a1[2] = (short)f2bb(p2.z); a1[3] = (short)f2bb(p2.w);
        a1[4] = (short)f2bb(p3.x); a1[5] = (short)f2bb(p3.y);
        a1[6] = (short)f2bb(p3.z); a1[7] = (short)f2bb(p3.w);
#pragma unroll
        for (int ct = 0; ct < 4; ++ct) {
            f32x4 acc = {0.f, 0.f, 0.f, 0.f};
            acc = mfma16(a0, wc[ct][0], acc);
            acc = mfma16(a1, wc[ct][1], acc);
            int colc = ct * 16 + lm;
#pragma unroll
            for (int r = 0; r < 4; ++r) {
                int grow = gr0 + w * 16 + lq * 4 + r;
                if (grow < n)
                    out[(size_t)grow * 64 + colc] = f2b(acc[r] + bv[ct]);
            }
        }
        p0 = q0; p1 = q1; p2 = q2; p3 = q3;
    }
}

// F=32 VALU body (round-3 proven shape), shared tiles passed in.
__device__ __forceinline__ void proj32_body(const float* __restrict__ x,
                                            const float* __restrict__ W,
                                            const float* __restrict__ b,
                                            bf16* __restrict__ out, int n, int bid,
                                            float (*sW)[64], float* sb, float (*sx)[32]) {
    const int F = 32;
    int tid = threadIdx.x;
    for (int idx = tid; idx < F * 16; idx += 256)          // F*64/4 float4s
        ((float4*)sW)[idx] = ((const float4*)W)[idx];
    if (tid < 64) sb[tid] = b[tid];
    int base = bid * 64;
    int w = tid >> 6, j = tid & 63;
    int lw = w * 4;
    for (int g = 0; g < 4; ++g) {
        int row0 = base + g * 16;
        __syncthreads();
        for (int idx = tid; idx < 4 * F; idx += 256) {
            int rr = idx / (F / 4), c4 = idx - rr * (F / 4);
            int row = row0 + rr;
            float4 v = (row < n) ? ((const float4*)x)[(size_t)row * (F / 4) + c4]
                                 : make_float4(0.f, 0.f, 0.f, 0.f);
            *(float4*)&sx[rr][c4 * 4] = v;
        }
        __syncthreads();
        float a0 = sb[j], a1 = sb[j], a2 = sb[j], a3 = sb[j];
#pragma unroll 2
        for (int k = 0; k < F; k += 4) {
            float w0 = sW[k][j], w1 = sW[k + 1][j], w2 = sW[k + 2][j], w3 = sW[k + 3][j];
            float4 m0 = *(const float4*)&sx[lw + 0][k];
            float4 m1 = *(const float4*)&sx[lw + 1][k];
            float4 m2 = *(const float4*)&sx[lw + 2][k];
            float4 m3 = *(const float4*)&sx[lw + 3][k];
            a0 += m0.x * w0 + m0.y * w1 + m0.z * w2 + m0.w * w3;
            a1 += m1.x * w0 + m1.y * w1 + m1.z * w2 + m1.w * w3;
            a2 += m2.x * w0 + m2.y * w1 + m2.z * w2 + m2.w * w3;
            a3 += m3.x * w0 + m3.y * w1 + m3.z * w2 + m3.w * w3;
        }
        int r0 = row0 + lw;
        if (r0 + 0 < n) out[(size_t)(r0 + 0) * 64 + j] = f2b(a0);
        if (r0 + 1 < n) out[(size_t)(r0 + 1) * 64 + j] = f2b(a1);
        if (r0 + 2 < n) out[(size_t)(r0 + 2) * 64 + j] = f2b(a2);
        if (r0 + 3 < n) out[(size_t)(r0 + 3) * 64 + j] = f2b(a3);
    }
}

// ======================= fused front: scatter + proj64 + proj32 ==============
// Three independent jobs in ONE launch so the latency-bound scatter (low VALU,
// no BW pressure) overlaps the compute-bound projections instead of
// serializing before them. Blocks [0,gsc): rank-based scatter (NO atomics);
// [gsc, gsc+gp64): proj64 MFMA; rest: proj32 VALU.
__global__ __launch_bounds__(256)
void fused_front_kernel(const int* __restrict__ src_tw, const int* __restrict__ dst_tw,
                        const int* __restrict__ rank_tw, const int* __restrict__ rp_w,
                        int* __restrict__ col_tw, int ne_tw,
                        const int* __restrict__ src_wt, const int* __restrict__ dst_wt,
                        const int* __restrict__ rank_wt, const int* __restrict__ rp_tx,
                        int* __restrict__ col_wt, int ne_wt, int gsc,
                        const float* __restrict__ x_tx, const float* __restrict__ Win_tx,
                        const float* __restrict__ bin_tx, bf16* __restrict__ A, int n_tx, int gp64,
                        const float* __restrict__ x_w, const float* __restrict__ Win_w,
                        const float* __restrict__ bin_w, bf16* __restrict__ B, int n_w) {
    __shared__ float sW32[32][64];
    __shared__ float sb32[64];
    __shared__ float sx32[16][32];
    int bid = blockIdx.x;
    if (bid < gsc) {
        int e = bid * 256 + threadIdx.x;
        if (e < ne_tw) {
            col_tw[rp_w[dst_tw[e]] + rank_tw[e]] = src_tw[e];
        } else {
            int e2 = e - ne_tw;
            if (e2 < ne_wt)
                col_wt[rp_tx[dst_wt[e2]] + rank_wt[e2]] = src_wt[e2];
        }
    } else if (bid < gsc + gp64) {
        proj64_body(x_tx, Win_tx, bin_tx, A, n_tx, bid - gsc);
    } else {
        proj32_body(x_w, Win_w, bin_w, B, n_w, bid - gsc - gp64, sW32, sb32, sx32);
    }
}

// ======================= gather mean (round-7 proven body) ===================
// mean[i,:] = (1/max(deg_i,1)) * sum_{e in row i} h[col[e], :]   (bf16 out)
// 8 rows/wave, 8 lanes/row, 8 features/lane; 16B bf16x8 loads; chunk-of-8
// clamped indices + {0,1} weights (bit-identical summation order).
#define GM_ACC(x, w) \
    a0 += (w) * b2fx(x, 0); a1 += (w) * b2fx(x, 1); \
    a2 += (w) * b2fx(x, 2); a3 += (w) * b2fx(x, 3); \
    a4 += (w) * b2fx(x, 4); a5 += (w) * b2fx(x, 5); \
    a6 += (w) * b2fx(x, 6); a7 += (w) * b2fx(x, 7);

__device__ __forceinline__ void gather_body(const bf16* __restrict__ h,
                                            const int* __restrict__ rowptr,
                                            const int* __restrict__ deg,
                                            const int* __restrict__ col,
                                            bf16* __restrict__ mean, int n, int bid) {
    int tid = threadIdx.x;
    int row = bid * 32 + (tid >> 3);          // 32 rows per block, 8 lanes each
    if (row >= n) return;
    int fg = tid & 7;                         // feature octet: cols fg*8..fg*8+7
    int base = rowptr[row];
    int d = deg[row];
    int lasto = (d > 0) ? d - 1 : 0;
    float a0 = 0.f, a1 = 0.f, a2 = 0.f, a3 = 0.f;
    float a4 = 0.f, a5 = 0.f, a6 = 0.f, a7 = 0.f;
    for (int e0 = 0; e0 < d; e0 += 8) {
        int o1 = (e0 + 1 < d) ? e0 + 1 : lasto;
        int o2 = (e0 + 2 < d) ? e0 + 2 : lasto;
        int o3 = (e0 + 3 < d) ? e0 + 3 : lasto;
        int o4 = (e0 + 4 < d) ? e0 + 4 : lasto;
        int o5 = (e0 + 5 < d) ? e0 + 5 : lasto;
        int o6 = (e0 + 6 < d) ? e0 + 6 : lasto;
        int o7 = (e0 + 7 < d) ? e0 + 7 : lasto;
        int s0 = col[base + e0], s1 = col[base + o1];
        int s2 = col[base + o2], s3 = col[base + o3];
        int s4 = col[base + o4], s5 = col[base + o5];
        int s6 = col[base + o6], s7 = col[base + o7];
        bf16x8 x0 = *(const bf16x8*)(h + ((size_t)s0 << 6) + (fg << 3));
        bf16x8 x1 = *(const bf16x8*)(h + ((size_t)s1 << 6) + (fg << 3));
        bf16x8 x2 = *(const bf16x8*)(h + ((size_t)s2 << 6) + (fg << 3));
        bf16x8 x3 = *(const bf16x8*)(h + ((size_t)s3 << 6) + (fg << 3));
        bf16x8 x4 = *(const bf16x8*)(h + ((size_t)s4 << 6) + (fg << 3));
        bf16x8 x5 = *(const bf16x8*)(h + ((size_t)s5 << 6) + (fg << 3));
        bf16x8 x6 = *(const bf16x8*)(h + ((size_t)s6 << 6) + (fg << 3));
        bf16x8 x7 = *(const bf16x8*)(h + ((size_t)s7 << 6) + (fg << 3));
        float w1 = (e0 + 1 < d) ? 1.f : 0.f;
        float w2 = (e0 + 2 < d) ? 1.f : 0.f;
        float w3 = (e0 + 3 < d) ? 1.f : 0.f;
        float w4 = (e0 + 4 < d) ? 1.f : 0.f;
        float w5 = (e0 + 5 < d) ? 1.f : 0.f;
        float w6 = (e0 + 6 < d) ? 1.f : 0.f;
        float w7 = (e0 + 7 < d) ? 1.f : 0.f;
        GM_ACC(x0, 1.f)
        GM_ACC(x1, w1)
        GM_ACC(x2, w2)
        GM_ACC(x3, w3)
        GM_ACC(x4, w4)
        GM_ACC(x5, w5)
        GM_ACC(x6, w6)
        GM_ACC(x7, w7)
    }
    float dd = fmaxf((float)d, 1.f);
    bf16x8 o;
    o[0] = (short)f2bb(a0 / dd); o[1] = (short)f2bb(a1 / dd);
    o[2] = (short)f2bb(a2 / dd); o[3] = (short)f2bb(a3 / dd);
    o[4] = (short)f2bb(a4 / dd); o[5] = (short)f2bb(a5 / dd);
    o[6] = (short)f2bb(a6 / dd); o[7] = (short)f2bb(a7 / dd);
    *(bf16x8*)(mean + ((size_t)row << 6) + (fg << 3)) = o;
}

// Merged: blocks [0,gbw) gather wallets, rest gather tx.
__global__ __launch_bounds__(256)
void gather2_kernel(const bf16* __restrict__ hw, const int* __restrict__ rpw,
                    const int* __restrict__ dw, const int* __restrict__ cw,
                    bf16* __restrict__ mw, int nw, int gbw,
                    const bf16* __restrict__ ht, const int* __restrict__ rpt,
                    const int* __restrict__ dt, const int* __restrict__ ct,
                    bf16* __restrict__ mt, int nt) {
    if ((int)blockIdx.x < gbw) gather_body(hw, rpw, dw, cw, mw, nw, blockIdx.x);
    else                       gather_body(ht, rpt, dt, ct, mt, nt, blockIdx.x - gbw);
}

// ======================= SAGE epilogue body (MFMA, LDS-free, pipelined) ======
// out[i,j] = relu( mean[i,:] . Wl[:,j] + bl[j] + xd[i,:] . Wr[:,j] )
// Per-wave streaming, next-group prefetch (disjoint rows -> in-place safe).
// HEAD: t2 restaged bf16 into sH (wave-local rows, per-wave LDS program
// order), K=64 MFMA GEMM + 16-lane shfl_xor reduce for the 64->2 contraction.
template<bool HEAD>
__device__ __forceinline__ void sage_body(
        const bf16* __restrict__ mean, const bf16* __restrict__ xd,
        const float* __restrict__ Wl, const float* __restrict__ bl,
        const float* __restrict__ Wr,
        float* __restrict__ outf, bf16* __restrict__ outb,
        const float* __restrict__ Wh1, const float* __restrict__ bh1,
        const float* __restrict__ Wh2, const float* __restrict__ bh2,
        float* __restrict__ logits, int n, int bid, short* sH) {
    int tid = threadIdx.x;
    int lane = tid & 63, w = tid >> 6;
    int lm = lane & 15, lq = lane >> 4;

    bf16x8 wc[4][4];   // [col-tile][k-step]; ks 0,1 = Wl(k0=0,32), ks 2,3 = Wr
    bf16x8 wh[4][2];
    float blv[4], h1v[4], w2a[4], w2b[4];
#pragma unroll
    for (int ct = 0; ct < 4; ++ct) {
        int colc = ct * 16 + lm;
        wc[ct][0] = load_bfrag(Wl, lq * 8, colc);
        wc[ct][1] = load_bfrag(Wl, 32 + lq * 8, colc);
        wc[ct][2] = load_bfrag(Wr, lq * 8, colc);
        wc[ct][3] = load_bfrag(Wr, 32 + lq * 8, colc);
        blv[ct] = bl[colc];
        if (HEAD) {
            wh[ct][0] = load_bfrag(Wh1, lq * 8, colc);
            wh[ct][1] = load_bfrag(Wh1, 32 + lq * 8, colc);
            h1v[ct] = bh1[colc];
            w2a[ct] = Wh2[colc * 2 + 0];
            w2b[ct] = Wh2[colc * 2 + 1];
        }
    }
    float b20 = 0.f, b21 = 0.f;
    if (HEAD) { b20 = bh2[0]; b21 = bh2[1]; }

    int larow = w * 16 + lm;             // local A-fragment row (0..63)
    int row0 = bid * 512;
    if (row0 >= n) return;
    int ar = row0 + larow; ar = (ar < n) ? ar : (n - 1);
    const bf16* mrow = mean + ((size_t)ar << 6);
    const bf16* xrow = xd + ((size_t)ar << 6);
    bf16x8 a0 = *(const bf16x8*)(mrow + lq * 8);        // mean k 0..31
    bf16x8 a1 = *(const bf16x8*)(mrow + 32 + lq * 8);   // mean k 32..63
    bf16x8 a2 = *(const bf16x8*)(xrow + lq * 8);        // xd   k 0..31
    bf16x8 a3 = *(const bf16x8*)(xrow + 32 + lq * 8);   // xd   k 32..63

    for (int g = 0; g < 8; ++g) {
        int gr0 = row0 + g * 64;
        if (gr0 >= n) break;
        bf16x8 n0 = a0, n1 = a1, n2 = a2, n3 = a3;
        if (g < 7) {   // prefetch next group (disjoint rows -> in-place safe)
            int nr = gr0 + 64 + larow; nr = (nr < n) ? nr : (n - 1);
            const bf16* nm = mean + ((size_t)nr << 6);
            const bf16* nx = xd + ((size_t)nr << 6);
            n0 = *(const bf16x8*)(nm + lq * 8);
            n1 = *(const bf16x8*)(nm + 32 + lq * 8);
            n2 = *(const bf16x8*)(nx + lq * 8);
            n3 = *(const bf16x8*)(nx + 32 + lq * 8);
        }
#pragma unroll
        for (int ct = 0; ct < 4; ++ct) {
            f32x4 acc = {0.f, 0.f, 0.f, 0.f};
            acc = mfma16(a0, wc[ct][0], acc);
            acc = mfma16(a1, wc[ct][1], acc);
            acc = mfma16(a2, wc[ct][2], acc);
            acc = mfma16(a3, wc[ct][3], acc);
            int colc = ct * 16 + lm;
#pragma unroll
            for (int r = 0; r < 4; ++r) {
                int lrow = w * 16 + lq * 4 + r;
                int grow = gr0 + lrow;
                float v = fmaxf(acc[r] + blv[ct], 0.f);
                if (grow < n) {
                    if (outf) outf[(size_t)grow * 64 + colc] = v;
                    if (outb) outb[(size_t)grow * 64 + colc] = f2b(v);
                }
                if (HEAD)   // wave-local restage; same wave reads below
                    *(short*)((char*)sH + swzH(lrow, colc * 2)) = (short)f2bb(v);
            }
        }
        if (HEAD) {
            bf16x8 h0 = *(const bf16x8*)((char*)sH + swzH(larow, lq * 16));
            bf16x8 h1 = *(const bf16x8*)((char*)sH + swzH(larow, 64 + lq * 16));
            float qa0 = 0.f, qa1 = 0.f, qa2 = 0.f, qa3 = 0.f;
            float qb0 = 0.f, qb1 = 0.f, qb2 = 0.f, qb3 = 0.f;
#pragma unroll
            for (int ct = 0; ct < 4; ++ct) {
                f32x4 acc = {0.f, 0.f, 0.f, 0.f};
                acc = mfma16(h0, wh[ct][0], acc);
                acc = mfma16(h1, wh[ct][1], acc);
                float hb = h1v[ct];
                float h_0 = fmaxf(acc[0] + hb, 0.f);
                float h_1 = fmaxf(acc[1] + hb, 0.f);
                float h_2 = fmaxf(acc[2] + hb, 0.f);
                float h_3 = fmaxf(acc[3] + hb, 0.f);
                qa0 += h_0 * w2a[ct]; qb0 += h_0 * w2b[ct];
                qa1 += h_1 * w2a[ct]; qb1 += h_1 * w2b[ct];
                qa2 += h_2 * w2a[ct]; qb2 += h_2 * w2b[ct];
                qa3 += h_3 * w2a[ct]; qb3 += h_3 * w2b[ct];
            }
#pragma unroll
            for (int m = 8; m; m >>= 1) {   // reduce over the 16-lane quad
                qa0 += __shfl_xor(qa0, m); qb0 += __shfl_xor(qb0, m);
                qa1 += __shfl_xor(qa1, m); qb1 += __shfl_xor(qb1, m);
                qa2 += __shfl_xor(qa2, m); qb2 += __shfl_xor(qb2, m);
                qa3 += __shfl_xor(qa3, m); qb3 += __shfl_xor(qb3, m);
            }
            int rowb = gr0 + w * 16 + lq * 4;
            if (lm == 0) {
                if (rowb + 0 < n) { logits[(size_t)(rowb + 0) * 2 + 0] = qa0 + b20;
                                    logits[(size_t)(rowb + 0) * 2 + 1] = qb0 + b21; }
                if (rowb + 1 < n) { logits[(size_t)(rowb + 1) * 2 + 0] = qa1 + b20;
                                    logits[(size_t)(rowb + 1) * 2 + 1] = qb1 + b21; }
                if (rowb + 2 < n) { logits[(size_t)(rowb + 2) * 2 + 0] = qa2 + b20;
                                    logits[(size_t)(rowb + 2) * 2 + 1] = qb2 + b21; }
                if (rowb + 3 < n) { logits[(size_t)(rowb + 3) * 2 + 0] = qa3 + b20;
                                    logits[(size_t)(rowb + 3) * 2 + 1] = qb3 + b21; }
            }
        }
        a0 = n0; a1 = n1; a2 = n2; a3 = n3;
    }
}

// Merged: blocks [0,gbw) run the wallet job (never HEAD), rest run the tx job.
template<bool HEAD>
__global__ __launch_bounds__(256, 2)
void sage2_kernel(const bf16* __restrict__ mw, const bf16* __restrict__ xw,
                  const float* __restrict__ Wlw, const float* __restrict__ blw,
                  const float* __restrict__ Wrw,
                  float* __restrict__ outfw, bf16* __restrict__ outbw, int nw, int gbw,
                  const bf16* __restrict__ mt, const bf16* __restrict__ xt,
                  const float* __restrict__ Wlt, const float* __restrict__ blt,
                  const float* __restrict__ Wrt,
                  float* __restrict__ outft, bf16* __restrict__ outbt,
                  const float* __restrict__ Wh1, const float* __restrict__ bh1,
                  const float* __restrict__ Wh2, const float* __restrict__ bh2,
                  float* __restrict__ logits, int nt) {
    __shared__ __align__(16) short sH[HEAD ? 64 * 64 : 8];
    if ((int)blockIdx.x < gbw)
        sage_body<false>(mw, xw, Wlw, blw, Wrw, outfw, outbw,
                         nullptr, nullptr, nullptr, nullptr, nullptr, nw, blockIdx.x, sH);
    else
        sage_body<HEAD>(mt, xt, Wlt, blt, Wrt, outft, outbt,
                        Wh1, bh1, Wh2, bh2, logits, nt, blockIdx.x - gbw, sH);
}

extern "C" void kernel_launch(void* const* d_in, const int* in_sizes, int n_in,
                              void* d_out, int out_size, void* d_ws, size_t ws_size,
                              hipStream_t stream) {
    const float* x_tx   = (const float*)d_in[0];
    const float* x_w    = (const float*)d_in[1];
    const int*   src_tw = (const int*)d_in[2];
    const int*   dst_tw = (const int*)d_in[3];
    const int*   src_wt = (const int*)d_in[4];
    const int*   dst_wt = (const int*)d_in[5];
    const float* Win_tx = (const float*)d_in[6];
    const float* bin_tx = (const float*)d_in[7];
    const float* Win_w  = (const float*)d_in[8];
    const float* bin_w  = (const float*)d_in[9];
    const float* Wl1_tw = (const float*)d_in[10];
    const float* bl1_tw = (const float*)d_in[11];
    const float* Wr1_tw = (const float*)d_in[12];
    const float* Wl1_wt = (const float*)d_in[13];
    const float* bl1_wt = (const float*)d_in[14];
    const float* Wr1_wt = (const float*)d_in[15];
    const float* Wl2_tw = (const float*)d_in[16];
    const float* bl2_tw = (const float*)d_in[17];
    const float* Wr2_tw = (const float*)d_in[18];
    const float* Wl2_wt = (const float*)d_in[19];
    const float* bl2_wt = (const float*)d_in[20];
    const float* Wr2_wt = (const float*)d_in[21];
    const float* Wh1    = (const float*)d_in[22];
    const float* bh1    = (const float*)d_in[23];
    const float* Wh2    = (const float*)d_in[24];
    const float* bh2    = (const float*)d_in[25];

    const int n_tx  = in_sizes[0] / 64;
    const int n_w   = in_sizes[1] / 32;
    const int ne_tw = in_sizes[2];
    const int ne_wt = in_sizes[4];

    // ---- workspace layout (~367 MB) ----
    bf16* mean_tx = (bf16*)d_ws;                          // n_tx*64 bf16 (128 MB)
    bf16* mean_w  = mean_tx + (size_t)n_tx * 64;          // n_w *64 bf16 ( 32 MB)
    bf16* A       = mean_w + (size_t)n_w * 64;            // n_tx*64 bf16: h_tx->t1 (in-place)
    bf16* B       = A + (size_t)n_tx * 64;                // n_w *64 bf16: h_w ->w1 (in-place)
    int*  deg_w   = (int*)(B + (size_t)n_w * 64);         // n_w
    int*  deg_tx  = deg_w + n_w;                          // n_tx
    int*  rp_w    = deg_tx + n_tx;                        // n_w
    int*  rp_tx   = rp_w + n_w;                           // n_tx
    int*  ex_w    = rp_tx + n_tx;                         // n_w  (scan scratch)
    int*  ex_tx   = ex_w + n_w;                           // n_tx
    int*  col_tw  = ex_tx + n_tx;                         // ne_tw
    int*  col_wt  = col_tw + ne_tw;                       // ne_wt
    int*  rank_tw = col_wt + ne_wt;                       // ne_tw
    int*  rank_wt = rank_tw + ne_tw;                      // ne_wt
    int*  part_w  = rank_wt + ne_wt;                      // <=4096
    int*  part_tx = part_w + 4096;                        // <=4096

    float* out_logits = (float*)d_out;
    float* out_t2 = out_logits + (size_t)n_tx * 2;
    float* out_w2 = out_t2 + (size_t)n_tx * 64;

    dim3 blk(256);
    int gp64 = (n_tx + 511) / 512;
    int gp32 = (n_w + 63) / 64;
    int gs_w  = (n_w + 511) / 512;
    int gs_tx = (n_tx + 511) / 512;
    int gg_w  = (n_w + 31) / 32;
    int gg_tx = (n_tx + 31) / 32;
    int gsc = (ne_tw + ne_wt + 255) / 256;
    int np_w  = (n_w + 1023) / 1024;
    int np_tx = (n_tx + 1023) / 1024;
    int nbw = (n_w + 255) / 256;
    int nbt = (n_tx + 255) / 256;

    // ---- CSR build: count+rank, scans (graph static, reused by both convs) ----
    hipMemsetAsync(deg_w, 0, (size_t)n_w * sizeof(int), stream);
    hipMemsetAsync(deg_tx, 0, (size_t)n_tx * sizeof(int), stream);
    count_rank2_kernel<<<gsc, blk, 0, stream>>>(dst_tw, deg_w, rank_tw, ne_tw,
                                                dst_wt, deg_tx, rank_wt, ne_wt);
    scan1m_kernel<<<np_w + np_tx, blk, 0, stream>>>(deg_w, ex_w, part_w, n_w, np_w,
                                                    deg_tx, ex_tx, part_tx, n_tx);
    scan2m_kernel<<<2, blk, 0, stream>>>(part_w, np_w, part_tx, np_tx);
    scan3m_kernel<<<nbw + nbt, blk, 0, stream>>>(ex_w, part_w, rp_w, n_w, nbw,
                                                 ex_tx, part_tx, rp_tx, n_tx);

    // ---- fused front: rank-scatter (no atomics) + proj64 + proj32, one launch ----
    fused_front_kernel<<<gsc + gp64 + gp32, blk, 0, stream>>>(
        src_tw, dst_tw, rank_tw, rp_w, col_tw, ne_tw,
        src_wt, dst_wt, rank_wt, rp_tx, col_wt, ne_wt, gsc,
        x_tx, Win_tx, bin_tx, A, n_tx, gp64,
        x_w, Win_w, bin_w, B, n_w);

    // ---- conv1: merged gathers, then merged sages (both in-place) ----
    gather2_kernel<<<gg_w + gg_tx, blk, 0, stream>>>(
        A, rp_w, deg_w, col_tw, mean_w, n_w, gg_w,
        B, rp_tx, deg_tx, col_wt, mean_tx, n_tx);
    sage2_kernel<false><<<gs_w + gs_tx, blk, 0, stream>>>(
        mean_w, B, Wl1_tw, bl1_tw, Wr1_tw, nullptr, B, n_w, gs_w,
        mean_tx, A, Wl1_wt, bl1_wt, Wr1_wt, nullptr, A,
        nullptr, nullptr, nullptr, nullptr, nullptr, n_tx);

    // ---- conv2: merged gathers, then merged sages (f32 outputs; tx has HEAD) ----
    gather2_kernel<<<gg_w + gg_tx, blk, 0, stream>>>(
        A, rp_w, deg_w, col_tw, mean_w, n_w, gg_w,
        B, rp_tx, deg_tx, col_wt, mean_tx, n_tx);
    sage2_kernel<true><<<gs_w + gs_tx, blk, 0, stream>>>(
        mean_w, B, Wl2_tw, bl2_tw, Wr2_tw, out_w2, nullptr, n_w, gs_w,
        mean_tx, A, Wl2_wt, bl2_wt, Wr2_wt, out_t2, nullptr,
        Wh1, bh1, Wh2, bh2, out_logits, n_tx);
}

// Round 12
// 1342.003 us; speedup vs baseline: 1.3159x; 1.0205x over previous
//
#include <hip/hip_runtime.h>
#include <hip/hip_bf16.h>

typedef __hip_bfloat16 bf16;
typedef __attribute__((ext_vector_type(8))) short bf16x8;   // 8 bf16 = 4 VGPR
typedef __attribute__((ext_vector_type(4))) float f32x4;    // MFMA accumulator

__device__ __forceinline__ float b2f(bf16 v) { return __bfloat162float(v); }
__device__ __forceinline__ bf16 f2b(float v) { return __float2bfloat16(v); }
__device__ __forceinline__ unsigned short f2bb(float v) {   // RNE f32->bf16 bits
    unsigned int u = __float_as_uint(v);
    u += 0x7fffu + ((u >> 16) & 1u);
    return (unsigned short)(u >> 16);
}
// bf16x8 element k (compile-time k) -> f32 via bit shift
__device__ __forceinline__ float b2fx(bf16x8 v, int k) {
    return __uint_as_float(((unsigned int)(unsigned short)v[k]) << 16);
}

__device__ __forceinline__ f32x4 mfma16(bf16x8 a, bf16x8 b, f32x4 c) {
    return __builtin_amdgcn_mfma_f32_16x16x32_bf16(a, b, c, 0, 0, 0);
}

// Gather a B-fragment: rows k0..k0+7 of column col from row-major W[64][64] f32.
__device__ __forceinline__ bf16x8 load_bfrag(const float* __restrict__ W, int k0, int col) {
    bf16x8 f;
#pragma unroll
    for (int j = 0; j < 8; ++j)
        f[j] = (short)f2bb(W[(size_t)(k0 + j) * 64 + col]);
    return f;
}

// Swizzled byte offset for the HEAD restage tile ([64][64 bf16], 128B rows).
__device__ __forceinline__ int swzH(int row, int b) {
    return row * 128 + (b ^ ((row & 7) << 4));
}

// ======================= CSR build =======================
// Count AND capture each edge's within-row rank (ticket). rank writes are
// SEQUENTIAL (e-indexed) -> cheap; this removes the atomic from the scatter.
__global__ void count_rank2_kernel(const int* __restrict__ dst_tw, int* __restrict__ deg_w,
                                   int* __restrict__ rank_tw, int ne_tw,
                                   const int* __restrict__ dst_wt, int* __restrict__ deg_tx,
                                   int* __restrict__ rank_wt, int ne_wt) {
    int e = blockIdx.x * 256 + threadIdx.x;
    if (e < ne_tw) rank_tw[e] = atomicAdd(&deg_w[dst_tw[e]], 1);
    else {
        int e2 = e - ne_tw;
        if (e2 < ne_wt) rank_wt[e2] = atomicAdd(&deg_tx[dst_wt[e2]], 1);
    }
}

// block-local exclusive scan over 1024 elems (256 thr x 4); writes block totals
__global__ void scan1m_kernel(const int* __restrict__ dw, int* __restrict__ ew,
                              int* __restrict__ pw, int nw, int npw,
                              const int* __restrict__ dt, int* __restrict__ et,
                              int* __restrict__ pt, int nt) {
    __shared__ int sT[256];
    const int* deg; int* excl; int* partial; int n; int b;
    if ((int)blockIdx.x < npw) { deg = dw; excl = ew; partial = pw; n = nw; b = blockIdx.x; }
    else { deg = dt; excl = et; partial = pt; n = nt; b = blockIdx.x - npw; }
    int tid = threadIdx.x;
    int base = b * 1024 + tid * 4;
    int v0 = (base + 0 < n) ? deg[base + 0] : 0;
    int v1 = (base + 1 < n) ? deg[base + 1] : 0;
    int v2 = (base + 2 < n) ? deg[base + 2] : 0;
    int v3 = (base + 3 < n) ? deg[base + 3] : 0;
    int t = v0 + v1 + v2 + v3;
    sT[tid] = t;
    __syncthreads();
    for (int off = 1; off < 256; off <<= 1) {   // Hillis-Steele inclusive
        int x = (tid >= off) ? sT[tid - off] : 0;
        __syncthreads();
        sT[tid] += x;
        __syncthreads();
    }
    int et2 = sT[tid] - t;
    if (tid == 255) partial[b] = sT[255];
    if (base + 0 < n) excl[base + 0] = et2;
    if (base + 1 < n) excl[base + 1] = et2 + v0;
    if (base + 2 < n) excl[base + 2] = et2 + v0 + v1;
    if (base + 3 < n) excl[base + 3] = et2 + v0 + v1 + v2;
}

// block 0 scans part_w, block 1 scans part_tx (each single-block full scan)
__global__ void scan2m_kernel(int* __restrict__ pw, int npw, int* __restrict__ pt, int npt) {
    __shared__ int sT[256];
    __shared__ int carry;
    int* partial = blockIdx.x ? pt : pw;
    int np = blockIdx.x ? npt : npw;
    int tid = threadIdx.x;
    if (tid == 0) carry = 0;
    __syncthreads();
    for (int c = 0; c < np; c += 256) {
        int i = c + tid;
        int v = (i < np) ? partial[i] : 0;
        sT[tid] = v;
        __syncthreads();
        for (int off = 1; off < 256; off <<= 1) {
            int x = (tid >= off) ? sT[tid - off] : 0;
            __syncthreads();
            sT[tid] += x;
            __syncthreads();
        }
        int incl = sT[tid];
        int total = sT[255];
        if (i < np) partial[i] = carry + incl - v;
        __syncthreads();
        if (tid == 0) carry += total;
        __syncthreads();
    }
}

// rowptr[i] = excl[i] + partial[i>>10]   (rank-based scatter needs no cursor)
__global__ void scan3m_kernel(const int* __restrict__ ew, const int* __restrict__ pw,
                              int* __restrict__ rw, int nw, int nbw,
                              const int* __restrict__ et, const int* __restrict__ pt,
                              int* __restrict__ rt, int nt) {
    int b = blockIdx.x;
    const int* excl; const int* partial; int* rp; int n; int i;
    if (b < nbw) { i = b * 256 + threadIdx.x; excl = ew; partial = pw; rp = rw; n = nw; }
    else { i = (b - nbw) * 256 + threadIdx.x; excl = et; partial = pt; rp = rt; n = nt; }
    if (i < n) rp[i] = excl[i] + partial[i >> 10];
}

// ======================= proj bodies (for the fused front) ===================
// F=64 MFMA body: LDS-free per-wave streaming with next-group prefetch.
__device__ __forceinline__ void proj64_body(const float* __restrict__ x,
                                            const float* __restrict__ W,
                                            const float* __restrict__ b,
                                            bf16* __restrict__ out, int n, int bid) {
    int tid = threadIdx.x;
    int lane = tid & 63, w = tid >> 6;
    int lm = lane & 15, lq = lane >> 4;

    bf16x8 wc[4][2];
    float bv[4];
#pragma unroll
    for (int ct = 0; ct < 4; ++ct) {
        int colc = ct * 16 + lm;
        wc[ct][0] = load_bfrag(W, lq * 8, colc);
        wc[ct][1] = load_bfrag(W, 32 + lq * 8, colc);
        bv[ct] = b[colc];
    }

    int larow = w * 16 + lm;
    int row0 = bid * 512;
    if (row0 >= n) return;
    int ar = row0 + larow; ar = (ar < n) ? ar : (n - 1);
    const float* xrow = x + ((size_t)ar << 6);
    float4 p0 = *(const float4*)(xrow + lq * 8);
    float4 p1 = *(const float4*)(xrow + lq * 8 + 4);
    float4 p2 = *(const float4*)(xrow + 32 + lq * 8);
    float4 p3 = *(const float4*)(xrow + 32 + lq * 8 + 4);

    for (int g = 0; g < 8; ++g) {
        int gr0 = row0 + g * 64;
        if (gr0 >= n) break;
        float4 q0 = p0, q1 = p1, q2 = p2, q3 = p3;
        if (g < 7) {   // prefetch next group
            int nr = gr0 + 64 + larow; nr = (nr < n) ? nr : (n - 1);
            const float* nx = x + ((size_t)nr << 6);
            q0 = *(const float4*)(nx + lq * 8);
            q1 = *(const float4*)(nx + lq * 8 + 4);
            q2 = *(const float4*)(nx + 32 + lq * 8);
            q3 = *(const float4*)(nx + 32 + lq * 8 + 4);
        }
        bf16x8 a0, a1;
        a0[0] = (short)f2bb(p0.x); a0[1] = (short)f2bb(p0.y);
        a0[2] = (short)f2bb(p0.z); a0[3] = (short)f2bb(p0.w);
        a0[4] = (short)f2bb(p1.x); a0[5] = (short)f2bb(p1.y);
        a0[6] = (short)f2bb(p1.z); a0[7] = (short)f2bb(p1.w);
        a1[0] = (short)f2bb(p2.x); a1[1] = (short)f2bb(p2.y);
        a1[2] = (short)f2bb(p2.z); a1[3] = (short)f2bb(p2.w);
        a1[4] = (short)f2bb(p3.x); a1[5] = (short)f2bb(p3.y);
        a1[6] = (short)f2bb(p3.z); a1[7] = (short)f2bb(p3.w);
#pragma unroll
        for (int ct = 0; ct < 4; ++ct) {
            f32x4 acc = {0.f, 0.f, 0.f, 0.f};
            acc = mfma16(a0, wc[ct][0], acc);
            acc = mfma16(a1, wc[ct][1], acc);
            int colc = ct * 16 + lm;
#pragma unroll
            for (int r = 0; r < 4; ++r) {
                int grow = gr0 + w * 16 + lq * 4 + r;
                if (grow < n)
                    out[(size_t)grow * 64 + colc] = f2b(acc[r] + bv[ct]);
            }
        }
        p0 = q0; p1 = q1; p2 = q2; p3 = q3;
    }
}

// F=32 VALU body (round-3 proven shape), shared tiles passed in.
__device__ __forceinline__ void proj32_body(const float* __restrict__ x,
                                            const float* __restrict__ W,
                                            const float* __restrict__ b,
                                            bf16* __restrict__ out, int n, int bid,
                                            float (*sW)[64], float* sb, float (*sx)[32]) {
    const int F = 32;
    int tid = threadIdx.x;
    for (int idx = tid; idx < F * 16; idx += 256)
        ((float4*)sW)[idx] = ((const float4*)W)[idx];
    if (tid < 64) sb[tid] = b[tid];
    int base = bid * 64;
    int w = tid >> 6, j = tid & 63;
    int lw = w * 4;
    for (int g = 0; g < 4; ++g) {
        int row0 = base + g * 16;
        __syncthreads();
        for (int idx = tid; idx < 4 * F; idx += 256) {
            int rr = idx / (F / 4), c4 = idx - rr * (F / 4);
            int row = row0 + rr;
            float4 v = (row < n) ? ((const float4*)x)[(size_t)row * (F / 4) + c4]
                                 : make_float4(0.f, 0.f, 0.f, 0.f);
            *(float4*)&sx[rr][c4 * 4] = v;
        }
        __syncthreads();
        float a0 = sb[j], a1 = sb[j], a2 = sb[j], a3 = sb[j];
#pragma unroll 2
        for (int k = 0; k < F; k += 4) {
            float w0 = sW[k][j], w1 = sW[k + 1][j], w2 = sW[k + 2][j], w3 = sW[k + 3][j];
            float4 m0 = *(const float4*)&sx[lw + 0][k];
            float4 m1 = *(const float4*)&sx[lw + 1][k];
            float4 m2 = *(const float4*)&sx[lw + 2][k];
            float4 m3 = *(const float4*)&sx[lw + 3][k];
            a0 += m0.x * w0 + m0.y * w1 + m0.z * w2 + m0.w * w3;
            a1 += m1.x * w0 + m1.y * w1 + m1.z * w2 + m1.w * w3;
            a2 += m2.x * w0 + m2.y * w1 + m2.z * w2 + m2.w * w3;
            a3 += m3.x * w0 + m3.y * w1 + m3.z * w2 + m3.w * w3;
        }
        int r0 = row0 + lw;
        if (r0 + 0 < n) out[(size_t)(r0 + 0) * 64 + j] = f2b(a0);
        if (r0 + 1 < n) out[(size_t)(r0 + 1) * 64 + j] = f2b(a1);
        if (r0 + 2 < n) out[(size_t)(r0 + 2) * 64 + j] = f2b(a2);
        if (r0 + 3 < n) out[(size_t)(r0 + 3) * 64 + j] = f2b(a3);
    }
}

// ======================= fused front: scatter + proj64 + proj32 ==============
// Blocks [0,gsc): rank-based scatter (NO atomics); [gsc,gsc+gp64): proj64;
// rest: proj32. Independent jobs overlap in one launch.
__global__ __launch_bounds__(256)
void fused_front_kernel(const int* __restrict__ src_tw, const int* __restrict__ dst_tw,
                        const int* __restrict__ rank_tw, const int* __restrict__ rp_w,
                        int* __restrict__ col_tw, int ne_tw,
                        const int* __restrict__ src_wt, const int* __restrict__ dst_wt,
                        const int* __restrict__ rank_wt, const int* __restrict__ rp_tx,
                        int* __restrict__ col_wt, int ne_wt, int gsc,
                        const float* __restrict__ x_tx, const float* __restrict__ Win_tx,
                        const float* __restrict__ bin_tx, bf16* __restrict__ A, int n_tx, int gp64,
                        const float* __restrict__ x_w, const float* __restrict__ Win_w,
                        const float* __restrict__ bin_w, bf16* __restrict__ B, int n_w) {
    __shared__ float sW32[32][64];
    __shared__ float sb32[64];
    __shared__ float sx32[16][32];
    int bid = blockIdx.x;
    if (bid < gsc) {
        int e = bid * 256 + threadIdx.x;
        if (e < ne_tw) {
            col_tw[rp_w[dst_tw[e]] + rank_tw[e]] = src_tw[e];
        } else {
            int e2 = e - ne_tw;
            if (e2 < ne_wt)
                col_wt[rp_tx[dst_wt[e2]] + rank_wt[e2]] = src_wt[e2];
        }
    } else if (bid < gsc + gp64) {
        proj64_body(x_tx, Win_tx, bin_tx, A, n_tx, bid - gsc);
    } else {
        proj32_body(x_w, Win_w, bin_w, B, n_w, bid - gsc - gp64, sW32, sb32, sx32);
    }
}

// ======== FUSED gather + SAGE (MFMA, LDS-free, barrier-free) ========
// out[i,j] = relu( mean_i . Wl[:,j] + bl[j] + xd[i,:] . Wr[:,j] ),
//   mean_i = (1/max(deg_i,1)) * sum_{e in CSR row i} hsrc[col[e], :]
// KEY: sage lane (lm,lq) needs exactly mean[row=gr0+w*16+lm][lq*8..+8] and
// [32+lq*8..+8] — two gather octets of ONE row — so the gather runs fully
// IN-LANE (16 f32 accums), no LDS, no barriers; each wave waits only on its
// own rows' edges while other waves' MFMA/stores co-schedule. The mean never
// touches HBM. Chunk-of-4 clamped edges + {0,1} weights (bounded liveness).
// NOT in-place: caller ping-pongs buffers (reads hsrc/xd, writes elsewhere).
// HEAD: t2 restaged bf16 into sH (wave-local rows, per-wave LDS program
// order), K=64 MFMA GEMM + 16-lane shfl_xor reduce for the 64->2 contraction.
#define GA4(x, wt) \
    p0 += (wt) * b2fx(x, 0); p1 += (wt) * b2fx(x, 1); \
    p2 += (wt) * b2fx(x, 2); p3 += (wt) * b2fx(x, 3); \
    p4 += (wt) * b2fx(x, 4); p5 += (wt) * b2fx(x, 5); \
    p6 += (wt) * b2fx(x, 6); p7 += (wt) * b2fx(x, 7);
#define GB4(x, wt) \
    q0 += (wt) * b2fx(x, 0); q1 += (wt) * b2fx(x, 1); \
    q2 += (wt) * b2fx(x, 2); q3 += (wt) * b2fx(x, 3); \
    q4 += (wt) * b2fx(x, 4); q5 += (wt) * b2fx(x, 5); \
    q6 += (wt) * b2fx(x, 6); q7 += (wt) * b2fx(x, 7);

template<bool HEAD>
__device__ __forceinline__ void sageg_body(
        const bf16* __restrict__ hsrc, const int* __restrict__ rowptr,
        const int* __restrict__ deg, const int* __restrict__ col,
        const bf16* __restrict__ xd,
        const float* __restrict__ Wl, const float* __restrict__ bl,
        const float* __restrict__ Wr,
        float* __restrict__ outf, bf16* __restrict__ outb,
        const float* __restrict__ Wh1, const float* __restrict__ bh1,
        const float* __restrict__ Wh2, const float* __restrict__ bh2,
        float* __restrict__ logits, int n, int bid, short* sH) {
    int tid = threadIdx.x;
    int lane = tid & 63, w = tid >> 6;
    int lm = lane & 15, lq = lane >> 4;

    bf16x8 wc[4][4];   // [col-tile][k-step]; ks 0,1 = Wl(k0=0,32), ks 2,3 = Wr
    bf16x8 wh[4][2];
    float blv[4], h1v[4], w2a[4], w2b[4];
#pragma unroll
    for (int ct = 0; ct < 4; ++ct) {
        int colc = ct * 16 + lm;
        wc[ct][0] = load_bfrag(Wl, lq * 8, colc);
        wc[ct][1] = load_bfrag(Wl, 32 + lq * 8, colc);
        wc[ct][2] = load_bfrag(Wr, lq * 8, colc);
        wc[ct][3] = load_bfrag(Wr, 32 + lq * 8, colc);
        blv[ct] = bl[colc];
        if (HEAD) {
            wh[ct][0] = load_bfrag(Wh1, lq * 8, colc);
            wh[ct][1] = load_bfrag(Wh1, 32 + lq * 8, colc);
            h1v[ct] = bh1[colc];
            w2a[ct] = Wh2[colc * 2 + 0];
            w2b[ct] = Wh2[colc * 2 + 1];
        }
    }
    float b20 = 0.f, b21 = 0.f;
    if (HEAD) { b20 = bh2[0]; b21 = bh2[1]; }

    int larow = w * 16 + lm;             // local A-fragment row (0..63)
    int row0 = bid * 512;
    if (row0 >= n) return;
    int fo1 = lq * 8, fo2 = 32 + lq * 8; // this lane's two feature octets

    for (int g = 0; g < 8; ++g) {
        int gr0 = row0 + g * 64;
        if (gr0 >= n) break;
        int arow = gr0 + larow;
        int ar = (arow < n) ? arow : (n - 1);
        // xd fragments: issue early so they're in flight during the gather
        const bf16* xrow = xd + ((size_t)ar << 6);
        bf16x8 a2 = *(const bf16x8*)(xrow + fo1);
        bf16x8 a3 = *(const bf16x8*)(xrow + fo2);
        // in-lane gather of row ar's two mean octets
        int base = rowptr[ar];
        int d = deg[ar];
        int lasto = (d > 0) ? d - 1 : 0;
        float p0 = 0.f, p1 = 0.f, p2 = 0.f, p3 = 0.f;
        float p4 = 0.f, p5 = 0.f, p6 = 0.f, p7 = 0.f;
        float q0 = 0.f, q1 = 0.f, q2 = 0.f, q3 = 0.f;
        float q4 = 0.f, q5 = 0.f, q6 = 0.f, q7 = 0.f;
        for (int e0 = 0; e0 < d; e0 += 4) {
            int o1 = (e0 + 1 < d) ? e0 + 1 : lasto;
            int o2 = (e0 + 2 < d) ? e0 + 2 : lasto;
            int o3 = (e0 + 3 < d) ? e0 + 3 : lasto;
            int s0 = col[base + e0], s1 = col[base + o1];
            int s2 = col[base + o2], s3 = col[base + o3];
            const bf16* r0p = hsrc + ((size_t)s0 << 6);
            const bf16* r1p = hsrc + ((size_t)s1 << 6);
            const bf16* r2p = hsrc + ((size_t)s2 << 6);
            const bf16* r3p = hsrc + ((size_t)s3 << 6);
            bf16x8 xa0 = *(const bf16x8*)(r0p + fo1);
            bf16x8 xb0 = *(const bf16x8*)(r0p + fo2);
            bf16x8 xa1 = *(const bf16x8*)(r1p + fo1);
            bf16x8 xb1 = *(const bf16x8*)(r1p + fo2);
            bf16x8 xa2 = *(const bf16x8*)(r2p + fo1);
            bf16x8 xb2 = *(const bf16x8*)(r2p + fo2);
            bf16x8 xa3 = *(const bf16x8*)(r3p + fo1);
            bf16x8 xb3 = *(const bf16x8*)(r3p + fo2);
            float w1 = (e0 + 1 < d) ? 1.f : 0.f;
            float w2 = (e0 + 2 < d) ? 1.f : 0.f;
            float w3 = (e0 + 3 < d) ? 1.f : 0.f;
            GA4(xa0, 1.f) GB4(xb0, 1.f)
            GA4(xa1, w1)  GB4(xb1, w1)
            GA4(xa2, w2)  GB4(xb2, w2)
            GA4(xa3, w3)  GB4(xb3, w3)
        }
        float dd = fmaxf((float)d, 1.f);
        bf16x8 a0, a1;
        a0[0] = (short)f2bb(p0 / dd); a0[1] = (short)f2bb(p1 / dd);
        a0[2] = (short)f2bb(p2 / dd); a0[3] = (short)f2bb(p3 / dd);
        a0[4] = (short)f2bb(p4 / dd); a0[5] = (short)f2bb(p5 / dd);
        a0[6] = (short)f2bb(p6 / dd); a0[7] = (short)f2bb(p7 / dd);
        a1[0] = (short)f2bb(q0 / dd); a1[1] = (short)f2bb(q1 / dd);
        a1[2] = (short)f2bb(q2 / dd); a1[3] = (short)f2bb(q3 / dd);
        a1[4] = (short)f2bb(q4 / dd); a1[5] = (short)f2bb(q5 / dd);
        a1[6] = (short)f2bb(q6 / dd); a1[7] = (short)f2bb(q7 / dd);

#pragma unroll
        for (int ct = 0; ct < 4; ++ct) {
            f32x4 acc = {0.f, 0.f, 0.f, 0.f};
            acc = mfma16(a0, wc[ct][0], acc);
            acc = mfma16(a1, wc[ct][1], acc);
            acc = mfma16(a2, wc[ct][2], acc);
            acc = mfma16(a3, wc[ct][3], acc);
            int colc = ct * 16 + lm;
#pragma unroll
            for (int r = 0; r < 4; ++r) {
                int lrow = w * 16 + lq * 4 + r;
                int grow = gr0 + lrow;
                float v = fmaxf(acc[r] + blv[ct], 0.f);
                if (grow < n) {
                    if (outf) outf[(size_t)grow * 64 + colc] = v;
                    if (outb) outb[(size_t)grow * 64 + colc] = f2b(v);
                }
                if (HEAD)   // wave-local restage; same wave reads below
                    *(short*)((char*)sH + swzH(lrow, colc * 2)) = (short)f2bb(v);
            }
        }
        if (HEAD) {
            bf16x8 h0 = *(const bf16x8*)((char*)sH + swzH(larow, lq * 16));
            bf16x8 h1 = *(const bf16x8*)((char*)sH + swzH(larow, 64 + lq * 16));
            float qa0 = 0.f, qa1 = 0.f, qa2 = 0.f, qa3 = 0.f;
            float qb0 = 0.f, qb1 = 0.f, qb2 = 0.f, qb3 = 0.f;
#pragma unroll
            for (int ct = 0; ct < 4; ++ct) {
                f32x4 acc = {0.f, 0.f, 0.f, 0.f};
                acc = mfma16(h0, wh[ct][0], acc);
                acc = mfma16(h1, wh[ct][1], acc);
                float hb = h1v[ct];
                float h_0 = fmaxf(acc[0] + hb, 0.f);
                float h_1 = fmaxf(acc[1] + hb, 0.f);
                float h_2 = fmaxf(acc[2] + hb, 0.f);
                float h_3 = fmaxf(acc[3] + hb, 0.f);
                qa0 += h_0 * w2a[ct]; qb0 += h_0 * w2b[ct];
                qa1 += h_1 * w2a[ct]; qb1 += h_1 * w2b[ct];
                qa2 += h_2 * w2a[ct]; qb2 += h_2 * w2b[ct];
                qa3 += h_3 * w2a[ct]; qb3 += h_3 * w2b[ct];
            }
#pragma unroll
            for (int m = 8; m; m >>= 1) {   // reduce over the 16-lane quad
                qa0 += __shfl_xor(qa0, m); qb0 += __shfl_xor(qb0, m);
                qa1 += __shfl_xor(qa1, m); qb1 += __shfl_xor(qb1, m);
                qa2 += __shfl_xor(qa2, m); qb2 += __shfl_xor(qb2, m);
                qa3 += __shfl_xor(qa3, m); qb3 += __shfl_xor(qb3, m);
            }
            int rowb = gr0 + w * 16 + lq * 4;
            if (lm == 0) {
                if (rowb + 0 < n) { logits[(size_t)(rowb + 0) * 2 + 0] = qa0 + b20;
                                    logits[(size_t)(rowb + 0) * 2 + 1] = qb0 + b21; }
                if (rowb + 1 < n) { logits[(size_t)(rowb + 1) * 2 + 0] = qa1 + b20;
                                    logits[(size_t)(rowb + 1) * 2 + 1] = qb1 + b21; }
                if (rowb + 2 < n) { logits[(size_t)(rowb + 2) * 2 + 0] = qa2 + b20;
                                    logits[(size_t)(rowb + 2) * 2 + 1] = qb2 + b21; }
                if (rowb + 3 < n) { logits[(size_t)(rowb + 3) * 2 + 0] = qa3 + b20;
                                    logits[(size_t)(rowb + 3) * 2 + 1] = qb3 + b21; }
            }
        }
    }
}

// Merged: blocks [0,gbw) run the wallet job (never HEAD), rest run the tx job.
template<bool HEAD>
__global__ __launch_bounds__(256)
void sageg2_kernel(const bf16* __restrict__ hw, const int* __restrict__ rpw,
                   const int* __restrict__ dgw, const int* __restrict__ clw,
                   const bf16* __restrict__ xw,
                   const float* __restrict__ Wlw, const float* __restrict__ blw,
                   const float* __restrict__ Wrw,
                   float* __restrict__ outfw, bf16* __restrict__ outbw, int nw, int gbw,
                   const bf16* __restrict__ ht, const int* __restrict__ rpt,
                   const int* __restrict__ dgt, const int* __restrict__ clt,
                   const bf16* __restrict__ xt,
                   const float* __restrict__ Wlt, const float* __restrict__ blt,
                   const float* __restrict__ Wrt,
                   float* __restrict__ outft, bf16* __restrict__ outbt,
                   const float* __restrict__ Wh1, const float* __restrict__ bh1,
                   const float* __restrict__ Wh2, const float* __restrict__ bh2,
                   float* __restrict__ logits, int nt) {
    __shared__ __align__(16) short sH[HEAD ? 64 * 64 : 8];
    if ((int)blockIdx.x < gbw)
        sageg_body<false>(hw, rpw, dgw, clw, xw, Wlw, blw, Wrw, outfw, outbw,
                          nullptr, nullptr, nullptr, nullptr, nullptr, nw, blockIdx.x, sH);
    else
        sageg_body<HEAD>(ht, rpt, dgt, clt, xt, Wlt, blt, Wrt, outft, outbt,
                         Wh1, bh1, Wh2, bh2, logits, nt, blockIdx.x - gbw, sH);
}

extern "C" void kernel_launch(void* const* d_in, const int* in_sizes, int n_in,
                              void* d_out, int out_size, void* d_ws, size_t ws_size,
                              hipStream_t stream) {
    const float* x_tx   = (const float*)d_in[0];
    const float* x_w    = (const float*)d_in[1];
    const int*   src_tw = (const int*)d_in[2];
    const int*   dst_tw = (const int*)d_in[3];
    const int*   src_wt = (const int*)d_in[4];
    const int*   dst_wt = (const int*)d_in[5];
    const float* Win_tx = (const float*)d_in[6];
    const float* bin_tx = (const float*)d_in[7];
    const float* Win_w  = (const float*)d_in[8];
    const float* bin_w  = (const float*)d_in[9];
    const float* Wl1_tw = (const float*)d_in[10];
    const float* bl1_tw = (const float*)d_in[11];
    const float* Wr1_tw = (const float*)d_in[12];
    const float* Wl1_wt = (const float*)d_in[13];
    const float* bl1_wt = (const float*)d_in[14];
    const float* Wr1_wt = (const float*)d_in[15];
    const float* Wl2_tw = (const float*)d_in[16];
    const float* bl2_tw = (const float*)d_in[17];
    const float* Wr2_tw = (const float*)d_in[18];
    const float* Wl2_wt = (const float*)d_in[19];
    const float* bl2_wt = (const float*)d_in[20];
    const float* Wr2_wt = (const float*)d_in[21];
    const float* Wh1    = (const float*)d_in[22];
    const float* bh1    = (const float*)d_in[23];
    const float* Wh2    = (const float*)d_in[24];
    const float* bh2    = (const float*)d_in[25];

    const int n_tx  = in_sizes[0] / 64;
    const int n_w   = in_sizes[1] / 32;
    const int ne_tw = in_sizes[2];
    const int ne_wt = in_sizes[4];

    // ---- workspace layout (~367 MB); A2/B2 are the conv ping-pong targets ----
    bf16* A2      = (bf16*)d_ws;                          // n_tx*64 bf16: t1
    bf16* B2      = A2 + (size_t)n_tx * 64;               // n_w *64 bf16: w1
    bf16* A       = B2 + (size_t)n_w * 64;                // n_tx*64 bf16: h_tx
    bf16* B       = A + (size_t)n_tx * 64;                // n_w *64 bf16: h_w
    int*  deg_w   = (int*)(B + (size_t)n_w * 64);         // n_w
    int*  deg_tx  = deg_w + n_w;                          // n_tx
    int*  rp_w    = deg_tx + n_tx;                        // n_w
    int*  rp_tx   = rp_w + n_w;                           // n_tx
    int*  ex_w    = rp_tx + n_tx;                         // n_w  (scan scratch)
    int*  ex_tx   = ex_w + n_w;                           // n_tx
    int*  col_tw  = ex_tx + n_tx;                         // ne_tw
    int*  col_wt  = col_tw + ne_tw;                       // ne_wt
    int*  rank_tw = col_wt + ne_wt;                       // ne_tw
    int*  rank_wt = rank_tw + ne_tw;                      // ne_wt
    int*  part_w  = rank_wt + ne_wt;                      // <=4096
    int*  part_tx = part_w + 4096;                        // <=4096

    float* out_logits = (float*)d_out;
    float* out_t2 = out_logits + (size_t)n_tx * 2;
    float* out_w2 = out_t2 + (size_t)n_tx * 64;

    dim3 blk(256);
    int gp64 = (n_tx + 511) / 512;
    int gp32 = (n_w + 63) / 64;
    int gs_w  = (n_w + 511) / 512;
    int gs_tx = (n_tx + 511) / 512;
    int gsc = (ne_tw + ne_wt + 255) / 256;
    int np_w  = (n_w + 1023) / 1024;
    int np_tx = (n_tx + 1023) / 1024;
    int nbw = (n_w + 255) / 256;
    int nbt = (n_tx + 255) / 256;

    // ---- CSR build: count+rank, scans (graph static, reused by both convs) ----
    hipMemsetAsync(deg_w, 0, (size_t)n_w * sizeof(int), stream);
    hipMemsetAsync(deg_tx, 0, (size_t)n_tx * sizeof(int), stream);
    count_rank2_kernel<<<gsc, blk, 0, stream>>>(dst_tw, deg_w, rank_tw, ne_tw,
                                                dst_wt, deg_tx, rank_wt, ne_wt);
    scan1m_kernel<<<np_w + np_tx, blk, 0, stream>>>(deg_w, ex_w, part_w, n_w, np_w,
                                                    deg_tx, ex_tx, part_tx, n_tx);
    scan2m_kernel<<<2, blk, 0, stream>>>(part_w, np_w, part_tx, np_tx);
    scan3m_kernel<<<nbw + nbt, blk, 0, stream>>>(ex_w, part_w, rp_w, n_w, nbw,
                                                 ex_tx, part_tx, rp_tx, n_tx);

    // ---- fused front: rank-scatter (no atomics) + proj64 + proj32, one launch ----
    fused_front_kernel<<<gsc + gp64 + gp32, blk, 0, stream>>>(
        src_tw, dst_tw, rank_tw, rp_w, col_tw, ne_tw,
        src_wt, dst_wt, rank_wt, rp_tx, col_wt, ne_wt, gsc,
        x_tx, Win_tx, bin_tx, A, n_tx, gp64,
        x_w, Win_w, bin_w, B, n_w);

    // ---- conv1 (fused gather+GEMM; reads A,B only, writes A2,B2) ----
    sageg2_kernel<false><<<gs_w + gs_tx, blk, 0, stream>>>(
        A, rp_w, deg_w, col_tw, B, Wl1_tw, bl1_tw, Wr1_tw, nullptr, B2, n_w, gs_w,
        B, rp_tx, deg_tx, col_wt, A, Wl1_wt, bl1_wt, Wr1_wt, nullptr, A2,
        nullptr, nullptr, nullptr, nullptr, nullptr, n_tx);

    // ---- conv2 (fused; reads A2,B2, writes f32 outputs; tx has HEAD) ----
    sageg2_kernel<true><<<gs_w + gs_tx, blk, 0, stream>>>(
        A2, rp_w, deg_w, col_tw, B2, Wl2_tw, bl2_tw, Wr2_tw, out_w2, nullptr, n_w, gs_w,
        B2, rp_tx, deg_tx, col_wt, A2, Wl2_wt, bl2_wt, Wr2_wt, out_t2, nullptr,
        Wh1, bh1, Wh2, bh2, out_logits, n_tx);
}